// Round 10
// baseline (433.683 us; speedup 1.0000x reference)
//
#include <hip/hip_runtime.h>

#define NN_ 131072
#define E_  2097152
#define B_  64
#define K_  20480
#define H_  512
#define EPS_ 1e-6f
#define DEGSCALE 4194304.0f      // 2^22
#define DEGINV   (1.0f / 4194304.0f)
#define NKC 128                  // fc1 K-split chunks
#define CHUNK 160                // K_ / NKC
#define KSTEPS 5                 // CHUNK / 32 (MFMA k=32 per step)
#define LSTR 40                  // fc1 LDS row stride in bf16 elems
#define NB 1024                  // CSR buckets
#define RPB 128                  // rows per bucket (NN/NB)
#define EB 4096                  // edges per p1 block (R15: 4096 for LDS-staged writeout)
#define P1B (E_ / EB)            // 512 p1 blocks
#define EPT (EB / 256)           // 16 edges per thread

typedef __attribute__((ext_vector_type(8))) short short8;   // 8 bf16 (4 VGPRs)
typedef __attribute__((ext_vector_type(4))) float f32x4;    // MFMA accumulator

// ---------------- graph preprocessing: bucket-sort CSR, ZERO global atomics ----
// R10: global atomics write through to HBM. 2-level bucket sort.
// R13: per-row edges sorted by column CHUNK (col>>14, 8 chunks) -> lap gathers
// sweep the column space roughly in lockstep, active band mostly L2-resident.
// R15: p1scat LDS-staged bucket-ordered writeout + packed recA.
// R18: fc1 cvtpk+prefetch, reg-budget-aware.
// R19: laps 4 lanes/row (edge-half s x channel-half h) for 2x MLP — but VGPR
// 52->68 crossed the 64-VGPR cliff (waves/CU halves above 64, m69): occupancy
// 35->19%, net neutral. R20: __launch_bounds__(512,8) caps VGPR at 64 ->
// 32 waves/CU cap restored; 4-lane MLP finally gets its occupancy.

__global__ __launch_bounds__(256) void k_p1hist(const int* __restrict__ ei, int* __restrict__ blockhist) {
  __shared__ int h[NB];
  int t = threadIdx.x, blk = blockIdx.x;
  for (int i = t; i < NB; i += 256) h[i] = 0;
  __syncthreads();
  int e0 = blk * EB;
#pragma unroll
  for (int i = 0; i < EPT; i++) {
    int r = ei[e0 + i * 256 + t];
    atomicAdd(&h[r >> 7], 1);
  }
  __syncthreads();
  for (int i = t; i < NB; i += 256) blockhist[blk * NB + i] = h[i];
}

// per-bucket exclusive scan over the P1B block counts (in place) + bucket totals
__global__ __launch_bounds__(256) void k_p1scanA(int* __restrict__ blockhist, int* __restrict__ btot) {
  __shared__ int s[256];
  int t = threadIdx.x, b = blockIdx.x;
  int v[P1B / 256], sum = 0;
#pragma unroll
  for (int j = 0; j < P1B / 256; j++) { v[j] = blockhist[((P1B / 256) * t + j) * NB + b]; sum += v[j]; }
  s[t] = sum;
  __syncthreads();
  for (int off = 1; off < 256; off <<= 1) {
    int x = (t >= off) ? s[t - off] : 0;
    __syncthreads();
    s[t] += x;
    __syncthreads();
  }
  int o = s[t] - sum;
#pragma unroll
  for (int j = 0; j < P1B / 256; j++) { blockhist[((P1B / 256) * t + j) * NB + b] = o; o += v[j]; }
  if (t == 0) btot[b] = s[255];
}

// exclusive scan of 1024 bucket totals -> bstart[0..NB], bstart[NB]=E
__global__ __launch_bounds__(256) void k_p1scanB(const int* __restrict__ btot, int* __restrict__ bstart) {
  __shared__ int s[256];
  int t = threadIdx.x;
  int v[4], sum = 0;
#pragma unroll
  for (int j = 0; j < 4; j++) { v[j] = btot[4 * t + j]; sum += v[j]; }
  s[t] = sum;
  __syncthreads();
  for (int off = 1; off < 256; off <<= 1) {
    int x = (t >= off) ? s[t - off] : 0;
    __syncthreads();
    s[t] += x;
    __syncthreads();
  }
  int o = s[t] - sum;
#pragma unroll
  for (int j = 0; j < 4; j++) { bstart[4 * t + j] = o; o += v[j]; }
  if (t == 0) bstart[NB] = s[255];
}

// R15: LDS-staged bucket-ordered scatter. Records packed (col | lr<<17, w).
__global__ __launch_bounds__(256) void k_p1scat(const int* __restrict__ ei, const float* __restrict__ ew,
                                                const int* __restrict__ blockhist, const int* __restrict__ bstart,
                                                int2* __restrict__ recA) {
  __shared__ int loff[NB], run[NB], base2[NB], sc[256];
  __shared__ int2 Ast[EB];                 // 32 KB bucket-sorted staging
  __shared__ unsigned short bst[EB];       // bucket id of staged record
  int t = threadIdx.x, blk = blockIdx.x;
  for (int i = t; i < NB; i += 256) {
    run[i] = 0;
    base2[i] = bstart[i] + blockhist[blk * NB + i];
  }
  __syncthreads();
  int e0 = blk * EB;
  int rv[EPT], cv[EPT];
  float wv[EPT];
#pragma unroll
  for (int i = 0; i < EPT; i++) {
    int e = e0 + i * 256 + t;
    rv[i] = ei[e];
    cv[i] = ei[E_ + e];
    wv[i] = ew[e];
    atomicAdd(&run[rv[i] >> 7], 1);        // local histogram
  }
  __syncthreads();
  // exclusive scan of the 1024-entry local histogram
  int v[4], sum = 0;
#pragma unroll
  for (int j = 0; j < 4; j++) { v[j] = run[4 * t + j]; sum += v[j]; }
  sc[t] = sum;
  __syncthreads();
  for (int off = 1; off < 256; off <<= 1) {
    int x = (t >= off) ? sc[t - off] : 0;
    __syncthreads();
    sc[t] += x;
    __syncthreads();
  }
  int o = sc[t] - sum;
#pragma unroll
  for (int j = 0; j < 4; j++) { loff[4 * t + j] = o; o += v[j]; }
  __syncthreads();
  for (int i = t; i < NB; i += 256) run[i] = 0;
  __syncthreads();
  // scatter into LDS in bucket order
#pragma unroll
  for (int i = 0; i < EPT; i++) {
    int bkt = rv[i] >> 7;
    int lpos = loff[bkt] + atomicAdd(&run[bkt], 1);
    Ast[lpos] = make_int2(cv[i] | ((rv[i] & 127) << 17), __float_as_int(wv[i]));
    bst[lpos] = (unsigned short)bkt;
  }
  __syncthreads();
  // linear writeout: consecutive i within a bucket -> consecutive global pos
  for (int i = t; i < EB; i += 256) {
    int bkt = bst[i];
    recA[base2[bkt] + (i - loff[bkt])] = Ast[i];
  }
}

// per-bucket: cell = localrow*8 + colchunk. Count cells + Q22 deg -> dinv /
// cnt / rowstart; scatter chunk-sorted ecsr (w = ew*dinv[r]).
__global__ __launch_bounds__(256) void k_p2(const int2* __restrict__ recA,
                                            const int* __restrict__ bstart,
                                            int* __restrict__ cnt_g, int* __restrict__ rowstart,
                                            float* __restrict__ dinv, int2* __restrict__ ecsr) {
  __shared__ int cnt_s[1024], excl_s[1024], run_s[1024], sc[256];
  __shared__ unsigned deg_s[RPB];
  __shared__ float dl[RPB];
  int t = threadIdx.x, b = blockIdx.x;
  int b0 = bstart[b], nE = bstart[b + 1] - b0;
  for (int j = t; j < 1024; j += 256) { cnt_s[j] = 0; run_s[j] = 0; }
  if (t < RPB) deg_s[t] = 0;
  __syncthreads();
  for (int i = t; i < nE; i += 256) {
    int2 ra = recA[b0 + i];
    int lr = ((unsigned)ra.x >> 17) & 127;
    int col = ra.x & 131071;
    float w = __int_as_float(ra.y);
    atomicAdd(&cnt_s[lr * 8 + ((unsigned)col >> 14)], 1);
    atomicAdd(&deg_s[lr], (unsigned)(w * DEGSCALE + 0.5f));
  }
  __syncthreads();
  int v[4], sum = 0;
#pragma unroll
  for (int j = 0; j < 4; j++) { v[j] = cnt_s[4 * t + j]; sum += v[j]; }
  sc[t] = sum;
  __syncthreads();
  for (int off = 1; off < 256; off <<= 1) {
    int x = (t >= off) ? sc[t - off] : 0;
    __syncthreads();
    sc[t] += x;
    __syncthreads();
  }
  int o = sc[t] - sum;
#pragma unroll
  for (int j = 0; j < 4; j++) { excl_s[4 * t + j] = o; o += v[j]; }
  __syncthreads();
  if (t < RPB) {
    int row = b * RPB + t;
    int e0r = excl_s[t * 8];
    int e1r = (t < RPB - 1) ? excl_s[t * 8 + 8] : nE;
    rowstart[row] = b0 + e0r;
    cnt_g[row] = e1r - e0r;
    float d = (float)deg_s[t] * DEGINV;
    float dv = (d > 0.f) ? rsqrtf(d + EPS_) : 0.f;
    dl[t] = dv;
    dinv[row] = dv;
  }
  __syncthreads();
  for (int i = t; i < nE; i += 256) {
    int2 ra = recA[b0 + i];
    int lr = ((unsigned)ra.x >> 17) & 127;
    int col = ra.x & 131071;
    int cell = lr * 8 + ((unsigned)col >> 14);
    int pos = excl_s[cell] + atomicAdd(&run_s[cell], 1);
    float wp = __int_as_float(ra.y) * dl[lr];
    ecsr[b0 + pos] = make_int2(col, __float_as_int(wp));
  }
}

// finalize w *= dinv[col]  (keeps lap kernels unchanged)
__global__ __launch_bounds__(256) void k_wfix(int2* __restrict__ ecsr, const float* __restrict__ dinv) {
  int e = blockIdx.x * 256 + threadIdx.x;
  if (e >= E_) return;
  int2 r = ecsr[e];
  r.y = __float_as_int(__int_as_float(r.y) * dinv[r.x]);
  ecsr[e] = r;
}

// ---------------- conv1 (complex 1x1 conv + ReLU) ----------------
// Y layout: [NN][20]  (0..9 real, 10..19 imag)

__global__ __launch_bounds__(256) void k_conv1(const float* __restrict__ xr, const float* __restrict__ xi,
                                               const float* __restrict__ wr_g, const float* __restrict__ wi_g,
                                               const float* __restrict__ br_g, const float* __restrict__ bi_g,
                                               float* __restrict__ Y) {
  __shared__ float wr[100], wi[100], br[10], bi[10];
  int t = threadIdx.x;
  if (t < 100) { wr[t] = wr_g[t]; wi[t] = wi_g[t]; }
  if (t < 10)  { br[t] = br_g[t]; bi[t] = bi_g[t]; }
  __syncthreads();
  int n = blockIdx.x * 256 + t;
  float xrv[10], xiv[10];
  const float2* a = (const float2*)(xr + (size_t)n * 10);
  const float2* b2 = (const float2*)(xi + (size_t)n * 10);
#pragma unroll
  for (int i = 0; i < 5; i++) {
    float2 v = a[i];  xrv[2 * i] = v.x; xrv[2 * i + 1] = v.y;
    float2 u = b2[i]; xiv[2 * i] = u.x; xiv[2 * i + 1] = u.y;
  }
  float out[20];
#pragma unroll
  for (int c = 0; c < 10; c++) {
    float ar = br[c], ai = bi[c];
#pragma unroll
    for (int tt = 0; tt < 10; tt++) {
      float wrc = wr[c * 10 + tt], wic = wi[c * 10 + tt];
      ar += xrv[tt] * wrc - xiv[tt] * wic;
      ai += xrv[tt] * wic + xiv[tt] * wrc;
    }
    out[c] = fmaxf(ar, 0.f);
    out[10 + c] = fmaxf(ai, 0.f);
  }
  float4* yp = (float4*)(Y + (size_t)n * 20);
#pragma unroll
  for (int i = 0; i < 5; i++)
    yp[i] = make_float4(out[4 * i], out[4 * i + 1], out[4 * i + 2], out[4 * i + 3]);
}

// ---------------- Laplacian pass 1: T1 = Y - S(Y) ----------------
// R19/R20: 4 lanes/row (n = gid>>2, s = edge half, h = channel half),
// shfl_xor(2) combine, VGPR capped at 64 via launch_bounds(512,8).

__global__ __launch_bounds__(512, 8) void k_lap1(const float* __restrict__ Y, const int2* __restrict__ ecsr,
                                                 const int* __restrict__ rowstart,
                                                 const int* __restrict__ cnt, float* __restrict__ T1) {
  int gid = blockIdx.x * 512 + threadIdx.x;
  int n = gid >> 2, s = (gid >> 1) & 1, h = gid & 1;
  float acc[10];
#pragma unroll
  for (int j = 0; j < 10; j++) acc[j] = 0.f;
  int e0 = rowstart[n], ec = cnt[n];
  int eh = ec >> 1;
  int lo = s ? eh : 0, hi = s ? ec : eh;
  int i = lo;
  for (; i + 2 <= hi; i += 2) {
    int2 ra = ecsr[e0 + i];
    int2 rb = ecsr[e0 + i + 1];
    float wa = __int_as_float(ra.y), wb = __int_as_float(rb.y);
    const float2* pa = (const float2*)(Y + (size_t)ra.x * 20 + h * 10);
    const float2* pb = (const float2*)(Y + (size_t)rb.x * 20 + h * 10);
    float2 va0 = pa[0], va1 = pa[1], va2 = pa[2], va3 = pa[3], va4 = pa[4];
    float2 vb0 = pb[0], vb1 = pb[1], vb2 = pb[2], vb3 = pb[3], vb4 = pb[4];
    acc[0] += wa * va0.x; acc[1] += wa * va0.y;
    acc[2] += wa * va1.x; acc[3] += wa * va1.y;
    acc[4] += wa * va2.x; acc[5] += wa * va2.y;
    acc[6] += wa * va3.x; acc[7] += wa * va3.y;
    acc[8] += wa * va4.x; acc[9] += wa * va4.y;
    acc[0] += wb * vb0.x; acc[1] += wb * vb0.y;
    acc[2] += wb * vb1.x; acc[3] += wb * vb1.y;
    acc[4] += wb * vb2.x; acc[5] += wb * vb2.y;
    acc[6] += wb * vb3.x; acc[7] += wb * vb3.y;
    acc[8] += wb * vb4.x; acc[9] += wb * vb4.y;
  }
  if (i < hi) {
    int2 rec = ecsr[e0 + i];
    float w = __int_as_float(rec.y);
    const float2* yp = (const float2*)(Y + (size_t)rec.x * 20 + h * 10);
#pragma unroll
    for (int q = 0; q < 5; q++) {
      float2 v = yp[q];
      acc[2 * q]     += w * v.x;
      acc[2 * q + 1] += w * v.y;
    }
  }
  // combine the two edge halves (partner lane differs in gid bit 1)
#pragma unroll
  for (int j = 0; j < 10; j++) acc[j] += __shfl_xor(acc[j], 2);
  if (s == 0) {
    const float2* yn = (const float2*)(Y + (size_t)n * 20 + h * 10);
    float2* tp = (float2*)(T1 + (size_t)n * 20 + h * 10);
#pragma unroll
    for (int q = 0; q < 5; q++) {
      float2 v = yn[q];
      tp[q] = make_float2(v.x - acc[2 * q], v.y - acc[2 * q + 1]);
    }
  }
}

// ---------------- Laplacian pass 2 + Chebyshev combine + ReLU ----------------

__global__ __launch_bounds__(512, 8) void k_lap2cheb(const float* __restrict__ Y, const float* __restrict__ T1,
                                                     const int2* __restrict__ ecsr,
                                                     const int* __restrict__ rowstart, const int* __restrict__ cnt,
                                                     const float* __restrict__ cw_g, const float* __restrict__ cb_g,
                                                     float* __restrict__ zr, float* __restrict__ zi) {
  __shared__ float cw[300], cb[10];
  int t = threadIdx.x;
  if (t < 300) cw[t] = cw_g[t];
  if (t < 10)  cb[t] = cb_g[t];
  __syncthreads();
  int gid = blockIdx.x * 512 + t;
  int n = gid >> 2, s = (gid >> 1) & 1, h = gid & 1;
  float acc[10];
#pragma unroll
  for (int j = 0; j < 10; j++) acc[j] = 0.f;
  int e0 = rowstart[n], ec = cnt[n];
  int eh = ec >> 1;
  int lo = s ? eh : 0, hi = s ? ec : eh;
  int i = lo;
  for (; i + 2 <= hi; i += 2) {
    int2 ra = ecsr[e0 + i];
    int2 rb = ecsr[e0 + i + 1];
    float wa = __int_as_float(ra.y), wb = __int_as_float(rb.y);
    const float2* pa = (const float2*)(T1 + (size_t)ra.x * 20 + h * 10);
    const float2* pb = (const float2*)(T1 + (size_t)rb.x * 20 + h * 10);
    float2 va0 = pa[0], va1 = pa[1], va2 = pa[2], va3 = pa[3], va4 = pa[4];
    float2 vb0 = pb[0], vb1 = pb[1], vb2 = pb[2], vb3 = pb[3], vb4 = pb[4];
    acc[0] += wa * va0.x; acc[1] += wa * va0.y;
    acc[2] += wa * va1.x; acc[3] += wa * va1.y;
    acc[4] += wa * va2.x; acc[5] += wa * va2.y;
    acc[6] += wa * va3.x; acc[7] += wa * va3.y;
    acc[8] += wa * va4.x; acc[9] += wa * va4.y;
    acc[0] += wb * vb0.x; acc[1] += wb * vb0.y;
    acc[2] += wb * vb1.x; acc[3] += wb * vb1.y;
    acc[4] += wb * vb2.x; acc[5] += wb * vb2.y;
    acc[6] += wb * vb3.x; acc[7] += wb * vb3.y;
    acc[8] += wb * vb4.x; acc[9] += wb * vb4.y;
  }
  if (i < hi) {
    int2 rec = ecsr[e0 + i];
    float w = __int_as_float(rec.y);
    const float2* tp = (const float2*)(T1 + (size_t)rec.x * 20 + h * 10);
#pragma unroll
    for (int q = 0; q < 5; q++) {
      float2 v = tp[q];
      acc[2 * q]     += w * v.x;
      acc[2 * q + 1] += w * v.y;
    }
  }
#pragma unroll
  for (int j = 0; j < 10; j++) acc[j] += __shfl_xor(acc[j], 2);

  float t0[10], t1v[10], t2[10];
  const float2* yn = (const float2*)(Y + (size_t)n * 20 + h * 10);
  const float2* tn = (const float2*)(T1 + (size_t)n * 20 + h * 10);
#pragma unroll
  for (int q = 0; q < 5; q++) {
    float2 v = yn[q]; t0[2 * q] = v.x; t0[2 * q + 1] = v.y;
    float2 u = tn[q]; t1v[2 * q] = u.x; t1v[2 * q + 1] = u.y;
  }
#pragma unroll
  for (int j = 0; j < 10; j++) t2[j] = 2.f * (t1v[j] - acc[j]) - t0[j];

  float outv[10];
#pragma unroll
  for (int o = 0; o < 10; o++) outv[o] = h ? 0.f : cb[o];
#pragma unroll
  for (int j = 0; j < 10; j++) {
#pragma unroll
    for (int o = 0; o < 10; o++) {
      outv[o] += t0[j] * cw[j * 10 + o] + t1v[j] * cw[100 + j * 10 + o] + t2[j] * cw[200 + j * 10 + o];
    }
  }
  if (s == 0) {
    float2* zp = (float2*)((h ? zi : zr) + (size_t)n * 10);
#pragma unroll
    for (int q = 0; q < 5; q++)
      zp[q] = make_float2(fmaxf(outv[2 * q], 0.f), fmaxf(outv[2 * q + 1], 0.f));
  }
}

// ---------------- fc1 complex GEMM: split-bf16 MFMA ----------------
// R18: cvtpk convert + issue-early prefetch, register-budget-aware:
// no bp[] table (4 base ptrs via arr=p>>1, row=(t>>3)+(p&1)*32, grp=t&7),
// plain launch_bounds (R17's (256,4) forced 64 VGPR -> scratch spills).

__device__ __forceinline__ unsigned cvtpk(float a, float b) {
  unsigned r;
  asm("v_cvt_pk_bf16_f32 %0, %1, %2" : "=v"(r) : "v"(a), "v"(b));
  return r;   // low16 = bf16(a), high16 = bf16(b)
}

#define LIDX(a, r, c) (((a) * 64 + (r)) * LSTR + (c))

__global__ __launch_bounds__(256) void k_fc1(const float* __restrict__ zr, const float* __restrict__ zi,
                                             const float* __restrict__ Wr, const float* __restrict__ Wi,
                                             float* __restrict__ pacc) {
  __shared__ unsigned short ls[8 * 64 * LSTR];   // 0 zrh,1 zrl,2 zih,3 zil,4 wrh,5 wrl,6 wih,7 wil
  int t = threadIdx.x;
  int hb = blockIdx.x;          // 0..7
  int kc = blockIdx.y;          // 0..NKC-1
  int H0 = hb * 64;
  int lane = t & 63, wv = t >> 6;
  int m = lane & 15, q = lane >> 4;

  // p = 0..7 decomposes as: arr = p>>1 (0 zr, 1 zi, 2 Wr, 3 Wi),
  // row = r0 + (p&1)*32 with r0 = t>>3, grp = t&7.
  int r0 = t >> 3, grp = t & 7;
  int colbase = kc * CHUNK + grp * 4;
  const float* pz  = zr + (size_t)r0 * K_ + colbase;
  const float* pzi = zi + (size_t)r0 * K_ + colbase;
  const float* pw  = Wr + (size_t)(H0 + r0) * K_ + colbase;
  const float* pwi = Wi + (size_t)(H0 + r0) * K_ + colbase;
  const size_t ROFF = (size_t)32 * K_;     // odd-p row offset (+32 rows)

  f32x4 p1[4], p2[4], p3[4], p4[4];
  f32x4 zero4 = {0.f, 0.f, 0.f, 0.f};
#pragma unroll
  for (int i = 0; i < 4; i++) { p1[i] = zero4; p2[i] = zero4; p3[i] = zero4; p4[i] = zero4; }

  float4 v[8];
#pragma unroll
  for (int p = 0; p < 8; p++) {
    const float* bases[4] = {pz, pzi, pw, pwi};
    v[p] = *(const float4*)(bases[p >> 1] + (p & 1) * ROFF);
  }

#pragma unroll 1
  for (int ks = 0; ks < KSTEPS; ks++) {
    // convert + LDS write of the chunk loaded last iteration
#pragma unroll
    for (int p = 0; p < 8; p++) {
      int arr = p >> 1;
      int row = r0 + (p & 1) * 32;
      float4 f = v[p];
      unsigned h01 = cvtpk(f.x, f.y);
      unsigned h23 = cvtpk(f.z, f.w);
      float l0 = f.x - __uint_as_float(h01 << 16);
      float l1 = f.y - __uint_as_float(h01 & 0xFFFF0000u);
      float l2 = f.z - __uint_as_float(h23 << 16);
      float l3 = f.w - __uint_as_float(h23 & 0xFFFF0000u);
      *(uint2*)&ls[LIDX(arr * 2,     row, grp * 4)] = make_uint2(h01, h23);
      *(uint2*)&ls[LIDX(arr * 2 + 1, row, grp * 4)] = make_uint2(cvtpk(l0, l1), cvtpk(l2, l3));
    }
    __syncthreads();
    // issue-early: next chunk's loads in flight during the MFMA section
    if (ks + 1 < KSTEPS) {
      int koff = (ks + 1) * 32;
#pragma unroll
      for (int p = 0; p < 8; p++) {
        const float* bases[4] = {pz, pzi, pw, pwi};
        v[p] = *(const float4*)(bases[p >> 1] + (p & 1) * ROFF + koff);
      }
    }

    short8 bwrh = *(const short8*)&ls[LIDX(4, wv * 16 + m, q * 8)];
    short8 bwrl = *(const short8*)&ls[LIDX(5, wv * 16 + m, q * 8)];
    short8 bwih = *(const short8*)&ls[LIDX(6, wv * 16 + m, q * 8)];
    short8 bwil = *(const short8*)&ls[LIDX(7, wv * 16 + m, q * 8)];
#pragma unroll
    for (int mt = 0; mt < 4; mt++) {
      short8 azrh = *(const short8*)&ls[LIDX(0, mt * 16 + m, q * 8)];
      short8 azrl = *(const short8*)&ls[LIDX(1, mt * 16 + m, q * 8)];
      short8 azih = *(const short8*)&ls[LIDX(2, mt * 16 + m, q * 8)];
      short8 azil = *(const short8*)&ls[LIDX(3, mt * 16 + m, q * 8)];
      p1[mt] = __builtin_amdgcn_mfma_f32_16x16x32_bf16(azrh, bwrh, p1[mt], 0, 0, 0);
      p2[mt] = __builtin_amdgcn_mfma_f32_16x16x32_bf16(azih, bwih, p2[mt], 0, 0, 0);
      p3[mt] = __builtin_amdgcn_mfma_f32_16x16x32_bf16(azrh, bwih, p3[mt], 0, 0, 0);
      p4[mt] = __builtin_amdgcn_mfma_f32_16x16x32_bf16(azih, bwrh, p4[mt], 0, 0, 0);
      p1[mt] = __builtin_amdgcn_mfma_f32_16x16x32_bf16(azrh, bwrl, p1[mt], 0, 0, 0);
      p2[mt] = __builtin_amdgcn_mfma_f32_16x16x32_bf16(azih, bwil, p2[mt], 0, 0, 0);
      p3[mt] = __builtin_amdgcn_mfma_f32_16x16x32_bf16(azrh, bwil, p3[mt], 0, 0, 0);
      p4[mt] = __builtin_amdgcn_mfma_f32_16x16x32_bf16(azih, bwrl, p4[mt], 0, 0, 0);
      p1[mt] = __builtin_amdgcn_mfma_f32_16x16x32_bf16(azrl, bwrh, p1[mt], 0, 0, 0);
      p2[mt] = __builtin_amdgcn_mfma_f32_16x16x32_bf16(azil, bwih, p2[mt], 0, 0, 0);
      p3[mt] = __builtin_amdgcn_mfma_f32_16x16x32_bf16(azrl, bwih, p3[mt], 0, 0, 0);
      p4[mt] = __builtin_amdgcn_mfma_f32_16x16x32_bf16(azil, bwrh, p4[mt], 0, 0, 0);
    }
    __syncthreads();
  }

#pragma unroll
  for (int mt = 0; mt < 4; mt++) {
#pragma unroll
    for (int i = 0; i < 4; i++) {
      int b = mt * 16 + q * 4 + i;
      int h = H0 + wv * 16 + m;
      *(float2*)&pacc[(((size_t)kc * 64 + b) * 512 + h) * 2] =
          make_float2(p1[mt][i] - p2[mt][i], p3[mt][i] + p4[mt][i]);
    }
  }
}

// ---------------- head, split for parallelism (R11) ----------------

__global__ __launch_bounds__(256) void k_red(const float* __restrict__ pacc, float* __restrict__ upart) {
  int b = blockIdx.x;            // 0..63
  int c = blockIdx.y;            // 0..1
  int s = blockIdx.z;            // 0..3 (kc quarter)
  int t = threadIdx.x;
  int h = c * 256 + t;           // 0..511
  float sr = 0.f, si = 0.f;
  int kc0 = s * (NKC / 4);
#pragma unroll 4
  for (int kc = kc0; kc < kc0 + NKC / 4; kc++) {
    float2 v = *(const float2*)&pacc[(((size_t)kc * 64 + b) * 512 + h) * 2];
    sr += v.x; si += v.y;
  }
  float* up = upart + ((size_t)s * 64 + b) * 1024;
  up[h] = sr;
  up[512 + h] = si;
}

__global__ __launch_bounds__(320) void k_head2(const float* __restrict__ upart,
                                               const float* __restrict__ br, const float* __restrict__ bi,
                                               const float* __restrict__ actor_w, const float* __restrict__ actor_b,
                                               const float* __restrict__ critic_w, const float* __restrict__ critic_b,
                                               float* __restrict__ out) {
  __shared__ float cs[1024];
  int b = blockIdx.x, t = threadIdx.x;
  for (int k = t; k < 1024; k += 320) {
    float s = 0.f;
#pragma unroll
    for (int s4 = 0; s4 < 4; s4++) s += upart[((size_t)s4 * 64 + b) * 1024 + k];
    float bias = (k < 512) ? br[k] : bi[k - 512];
    cs[k] = fmaxf(s + bias, 0.f);
  }
  __syncthreads();
  if (t < 264) {                               // 33 outputs x 8 lanes
    int o = t >> 3, r = t & 7;
    const float* w = (o < 32) ? (actor_w + o * 1024) : critic_w;
    float acc = 0.f;
    const int j0 = r * 128;
#pragma unroll 8
    for (int j = 0; j < 128; j++) acc += cs[j0 + j] * w[j0 + j];
    acc += __shfl_down(acc, 4, 8);
    acc += __shfl_down(acc, 2, 8);
    acc += __shfl_down(acc, 1, 8);
    if (r == 0) {
      acc += (o < 32) ? actor_b[o] : critic_b[0];
      if (o < 32) out[b * 32 + o] = acc;
      else        out[2048 + b] = acc;
    }
  }
}

// ---------------- launch ----------------

extern "C" void kernel_launch(void* const* d_in, const int* in_sizes, int n_in,
                              void* d_out, int out_size, void* d_ws, size_t ws_size,
                              hipStream_t stream) {
  const float* xr   = (const float*)d_in[0];
  const float* xi   = (const float*)d_in[1];
  const float* ew   = (const float*)d_in[2];
  const float* c1wr = (const float*)d_in[3];
  const float* c1wi = (const float*)d_in[4];
  const float* c1br = (const float*)d_in[5];
  const float* c1bi = (const float*)d_in[6];
  const float* chw  = (const float*)d_in[7];
  const float* chb  = (const float*)d_in[8];
  const float* f1wr = (const float*)d_in[9];
  const float* f1wi = (const float*)d_in[10];
  const float* f1br = (const float*)d_in[11];
  const float* f1bi = (const float*)d_in[12];
  const float* cw   = (const float*)d_in[13];
  const float* cb   = (const float*)d_in[14];
  const float* aw   = (const float*)d_in[15];
  const float* ab   = (const float*)d_in[16];
  const int*   ei   = (const int*)d_in[17];
  float* out = (float*)d_out;

  char* ws = (char*)d_ws;
  size_t off = 0;
  auto alloc = [&](size_t bytes) { char* p = ws + off; off += (bytes + 255) & ~(size_t)255; return p; };
  int*   cnt      = (int*)  alloc((size_t)NN_ * 4);
  int*   rowstart = (int*)  alloc((size_t)NN_ * 4);
  float* dinv     = (float*)alloc((size_t)NN_ * 4);
  int*   btot     = (int*)  alloc((size_t)NB * 4);
  int*   bstart   = (int*)  alloc((size_t)(NB + 1) * 4);
  float* zr       = (float*)alloc((size_t)NN_ * 10 * 4);
  float* zi       = (float*)alloc((size_t)NN_ * 10 * 4);
  int2*  ecsr     = (int2*) alloc((size_t)E_ * 8);    // born at k_p2; dead after lap2cheb
  float* Y        = (float*)alloc((size_t)NN_ * 20 * 4);   // born at conv1
  float* T1       = (float*)alloc((size_t)NN_ * 20 * 4);   // born at lap1 (contiguous after Y)
  // blockhist (2 MB, dead after p1scat) aliases ecsr head (ecsr born at k_p2)
  int* blockhist = (int*)ecsr;
  // recA (16 MB), dead after k_p2, aliases Y+T1 (contiguous 21 MB)
  int2* recA = (int2*)Y;
  // pacc (33.5 MB, born at fc1) aliases ecsr+Y+T1 (37.8 MB, all dead by then)
  float* pacc = (float*)ecsr;
  // upart (1 MB, born at k_red) aliases zr (5.2 MB, dead after fc1)
  float* upart = (float*)zr;

  k_p1hist<<<P1B, 256, 0, stream>>>(ei, blockhist);
  k_p1scanA<<<NB, 256, 0, stream>>>(blockhist, btot);
  k_p1scanB<<<1, 256, 0, stream>>>(btot, bstart);
  k_p1scat<<<P1B, 256, 0, stream>>>(ei, ew, blockhist, bstart, recA);
  k_p2<<<NB, 256, 0, stream>>>(recA, bstart, cnt, rowstart, dinv, ecsr);
  k_wfix<<<E_ / 256, 256, 0, stream>>>(ecsr, dinv);
  k_conv1<<<NN_ / 256, 256, 0, stream>>>(xr, xi, c1wr, c1wi, c1br, c1bi, Y);
  k_lap1<<<NN_ * 4 / 512, 512, 0, stream>>>(Y, ecsr, rowstart, cnt, T1);
  k_lap2cheb<<<NN_ * 4 / 512, 512, 0, stream>>>(Y, T1, ecsr, rowstart, cnt, chw, chb, zr, zi);
  k_fc1<<<dim3(8, NKC), 256, 0, stream>>>(zr, zi, f1wr, f1wi, pacc);
  k_red<<<dim3(64, 2, 4), 256, 0, stream>>>(pacc, upart);
  k_head2<<<B_, 320, 0, stream>>>(upart, f1br, f1bi, aw, ab, cw, cb, out);
}

// Round 11
// 340.560 us; speedup vs baseline: 1.2734x; 1.2734x over previous
//
#include <hip/hip_runtime.h>

#define NN_ 131072
#define E_  2097152
#define B_  64
#define K_  20480
#define H_  512
#define EPS_ 1e-6f
#define DEGSCALE 4194304.0f      // 2^22
#define DEGINV   (1.0f / 4194304.0f)
#define NKC 128                  // fc1 K-split chunks
#define CHUNK 160                // K_ / NKC
#define KSTEPS 5                 // CHUNK / 32 (MFMA k=32 per step)
#define LSTR 40                  // fc1 LDS row stride in bf16 elems
#define NB 1024                  // CSR buckets
#define RPB 128                  // rows per bucket (NN/NB)
#define EB 4096                  // edges per p1 block (R15: 4096 for LDS-staged writeout)
#define P1B (E_ / EB)            // 512 p1 blocks
#define EPT (EB / 256)           // 16 edges per thread

typedef __attribute__((ext_vector_type(8))) short short8;   // 8 bf16 (4 VGPRs)
typedef __attribute__((ext_vector_type(4))) float f32x4;    // MFMA accumulator
typedef __attribute__((ext_vector_type(2))) _Float16 half2v; // 2 fp16 in 4B

// ---------------- graph preprocessing: bucket-sort CSR, ZERO global atomics ----
// R10: global atomics write through to HBM. 2-level bucket sort.
// R13: per-row edges sorted by column CHUNK (col>>14, 8 chunks) -> lap gathers
// sweep the column space roughly in lockstep, active band mostly L2-resident.
// R15: p1scat LDS-staged bucket-ordered writeout + packed recA.
// R18: fc1 cvtpk+prefetch, reg-budget-aware.
// R19/R20 parallelism experiments FALSIFIED the latency theory: delivered BW
// pinned ~3.3 TB/s at occ 19/35/76% -> random-64B-line HBM ceiling. (R20's
// (512,8) bound also forced 32 VGPR -> spill avalanche, WRITE 10->133MB.)
// R21: revert laps to R18 2-lane form; halve gather BYTES via fp16 shadow
// copies (Yh/T1h, 40B rows) for the gathered neighbor values only. All
// own-row reads + cheb + z + fc1 stay fp32 (error enters once per edge-sum).

__global__ __launch_bounds__(256) void k_p1hist(const int* __restrict__ ei, int* __restrict__ blockhist) {
  __shared__ int h[NB];
  int t = threadIdx.x, blk = blockIdx.x;
  for (int i = t; i < NB; i += 256) h[i] = 0;
  __syncthreads();
  int e0 = blk * EB;
#pragma unroll
  for (int i = 0; i < EPT; i++) {
    int r = ei[e0 + i * 256 + t];
    atomicAdd(&h[r >> 7], 1);
  }
  __syncthreads();
  for (int i = t; i < NB; i += 256) blockhist[blk * NB + i] = h[i];
}

// per-bucket exclusive scan over the P1B block counts (in place) + bucket totals
__global__ __launch_bounds__(256) void k_p1scanA(int* __restrict__ blockhist, int* __restrict__ btot) {
  __shared__ int s[256];
  int t = threadIdx.x, b = blockIdx.x;
  int v[P1B / 256], sum = 0;
#pragma unroll
  for (int j = 0; j < P1B / 256; j++) { v[j] = blockhist[((P1B / 256) * t + j) * NB + b]; sum += v[j]; }
  s[t] = sum;
  __syncthreads();
  for (int off = 1; off < 256; off <<= 1) {
    int x = (t >= off) ? s[t - off] : 0;
    __syncthreads();
    s[t] += x;
    __syncthreads();
  }
  int o = s[t] - sum;
#pragma unroll
  for (int j = 0; j < P1B / 256; j++) { blockhist[((P1B / 256) * t + j) * NB + b] = o; o += v[j]; }
  if (t == 0) btot[b] = s[255];
}

// exclusive scan of 1024 bucket totals -> bstart[0..NB], bstart[NB]=E
__global__ __launch_bounds__(256) void k_p1scanB(const int* __restrict__ btot, int* __restrict__ bstart) {
  __shared__ int s[256];
  int t = threadIdx.x;
  int v[4], sum = 0;
#pragma unroll
  for (int j = 0; j < 4; j++) { v[j] = btot[4 * t + j]; sum += v[j]; }
  s[t] = sum;
  __syncthreads();
  for (int off = 1; off < 256; off <<= 1) {
    int x = (t >= off) ? s[t - off] : 0;
    __syncthreads();
    s[t] += x;
    __syncthreads();
  }
  int o = s[t] - sum;
#pragma unroll
  for (int j = 0; j < 4; j++) { bstart[4 * t + j] = o; o += v[j]; }
  if (t == 0) bstart[NB] = s[255];
}

// R15: LDS-staged bucket-ordered scatter. Records packed (col | lr<<17, w).
__global__ __launch_bounds__(256) void k_p1scat(const int* __restrict__ ei, const float* __restrict__ ew,
                                                const int* __restrict__ blockhist, const int* __restrict__ bstart,
                                                int2* __restrict__ recA) {
  __shared__ int loff[NB], run[NB], base2[NB], sc[256];
  __shared__ int2 Ast[EB];                 // 32 KB bucket-sorted staging
  __shared__ unsigned short bst[EB];       // bucket id of staged record
  int t = threadIdx.x, blk = blockIdx.x;
  for (int i = t; i < NB; i += 256) {
    run[i] = 0;
    base2[i] = bstart[i] + blockhist[blk * NB + i];
  }
  __syncthreads();
  int e0 = blk * EB;
  int rv[EPT], cv[EPT];
  float wv[EPT];
#pragma unroll
  for (int i = 0; i < EPT; i++) {
    int e = e0 + i * 256 + t;
    rv[i] = ei[e];
    cv[i] = ei[E_ + e];
    wv[i] = ew[e];
    atomicAdd(&run[rv[i] >> 7], 1);        // local histogram
  }
  __syncthreads();
  // exclusive scan of the 1024-entry local histogram
  int v[4], sum = 0;
#pragma unroll
  for (int j = 0; j < 4; j++) { v[j] = run[4 * t + j]; sum += v[j]; }
  sc[t] = sum;
  __syncthreads();
  for (int off = 1; off < 256; off <<= 1) {
    int x = (t >= off) ? sc[t - off] : 0;
    __syncthreads();
    sc[t] += x;
    __syncthreads();
  }
  int o = sc[t] - sum;
#pragma unroll
  for (int j = 0; j < 4; j++) { loff[4 * t + j] = o; o += v[j]; }
  __syncthreads();
  for (int i = t; i < NB; i += 256) run[i] = 0;
  __syncthreads();
  // scatter into LDS in bucket order
#pragma unroll
  for (int i = 0; i < EPT; i++) {
    int bkt = rv[i] >> 7;
    int lpos = loff[bkt] + atomicAdd(&run[bkt], 1);
    Ast[lpos] = make_int2(cv[i] | ((rv[i] & 127) << 17), __float_as_int(wv[i]));
    bst[lpos] = (unsigned short)bkt;
  }
  __syncthreads();
  // linear writeout: consecutive i within a bucket -> consecutive global pos
  for (int i = t; i < EB; i += 256) {
    int bkt = bst[i];
    recA[base2[bkt] + (i - loff[bkt])] = Ast[i];
  }
}

// per-bucket: cell = localrow*8 + colchunk. Count cells + Q22 deg -> dinv /
// cnt / rowstart; scatter chunk-sorted ecsr (w = ew*dinv[r]).
__global__ __launch_bounds__(256) void k_p2(const int2* __restrict__ recA,
                                            const int* __restrict__ bstart,
                                            int* __restrict__ cnt_g, int* __restrict__ rowstart,
                                            float* __restrict__ dinv, int2* __restrict__ ecsr) {
  __shared__ int cnt_s[1024], excl_s[1024], run_s[1024], sc[256];
  __shared__ unsigned deg_s[RPB];
  __shared__ float dl[RPB];
  int t = threadIdx.x, b = blockIdx.x;
  int b0 = bstart[b], nE = bstart[b + 1] - b0;
  for (int j = t; j < 1024; j += 256) { cnt_s[j] = 0; run_s[j] = 0; }
  if (t < RPB) deg_s[t] = 0;
  __syncthreads();
  for (int i = t; i < nE; i += 256) {
    int2 ra = recA[b0 + i];
    int lr = ((unsigned)ra.x >> 17) & 127;
    int col = ra.x & 131071;
    float w = __int_as_float(ra.y);
    atomicAdd(&cnt_s[lr * 8 + ((unsigned)col >> 14)], 1);
    atomicAdd(&deg_s[lr], (unsigned)(w * DEGSCALE + 0.5f));
  }
  __syncthreads();
  int v[4], sum = 0;
#pragma unroll
  for (int j = 0; j < 4; j++) { v[j] = cnt_s[4 * t + j]; sum += v[j]; }
  sc[t] = sum;
  __syncthreads();
  for (int off = 1; off < 256; off <<= 1) {
    int x = (t >= off) ? sc[t - off] : 0;
    __syncthreads();
    sc[t] += x;
    __syncthreads();
  }
  int o = sc[t] - sum;
#pragma unroll
  for (int j = 0; j < 4; j++) { excl_s[4 * t + j] = o; o += v[j]; }
  __syncthreads();
  if (t < RPB) {
    int row = b * RPB + t;
    int e0r = excl_s[t * 8];
    int e1r = (t < RPB - 1) ? excl_s[t * 8 + 8] : nE;
    rowstart[row] = b0 + e0r;
    cnt_g[row] = e1r - e0r;
    float d = (float)deg_s[t] * DEGINV;
    float dv = (d > 0.f) ? rsqrtf(d + EPS_) : 0.f;
    dl[t] = dv;
    dinv[row] = dv;
  }
  __syncthreads();
  for (int i = t; i < nE; i += 256) {
    int2 ra = recA[b0 + i];
    int lr = ((unsigned)ra.x >> 17) & 127;
    int col = ra.x & 131071;
    int cell = lr * 8 + ((unsigned)col >> 14);
    int pos = excl_s[cell] + atomicAdd(&run_s[cell], 1);
    float wp = __int_as_float(ra.y) * dl[lr];
    ecsr[b0 + pos] = make_int2(col, __float_as_int(wp));
  }
}

// finalize w *= dinv[col]  (keeps lap kernels unchanged)
__global__ __launch_bounds__(256) void k_wfix(int2* __restrict__ ecsr, const float* __restrict__ dinv) {
  int e = blockIdx.x * 256 + threadIdx.x;
  if (e >= E_) return;
  int2 r = ecsr[e];
  r.y = __float_as_int(__int_as_float(r.y) * dinv[r.x]);
  ecsr[e] = r;
}

// ---------------- conv1 (complex 1x1 conv + ReLU) ----------------
// Y layout: [NN][20] fp32 (0..9 real, 10..19 imag) + Yh fp16 shadow [NN][20]h.

__global__ __launch_bounds__(256) void k_conv1(const float* __restrict__ xr, const float* __restrict__ xi,
                                               const float* __restrict__ wr_g, const float* __restrict__ wi_g,
                                               const float* __restrict__ br_g, const float* __restrict__ bi_g,
                                               float* __restrict__ Y, unsigned* __restrict__ Yh) {
  __shared__ float wr[100], wi[100], br[10], bi[10];
  int t = threadIdx.x;
  if (t < 100) { wr[t] = wr_g[t]; wi[t] = wi_g[t]; }
  if (t < 10)  { br[t] = br_g[t]; bi[t] = bi_g[t]; }
  __syncthreads();
  int n = blockIdx.x * 256 + t;
  float xrv[10], xiv[10];
  const float2* a = (const float2*)(xr + (size_t)n * 10);
  const float2* b2 = (const float2*)(xi + (size_t)n * 10);
#pragma unroll
  for (int i = 0; i < 5; i++) {
    float2 v = a[i];  xrv[2 * i] = v.x; xrv[2 * i + 1] = v.y;
    float2 u = b2[i]; xiv[2 * i] = u.x; xiv[2 * i + 1] = u.y;
  }
  float out[20];
#pragma unroll
  for (int c = 0; c < 10; c++) {
    float ar = br[c], ai = bi[c];
#pragma unroll
    for (int tt = 0; tt < 10; tt++) {
      float wrc = wr[c * 10 + tt], wic = wi[c * 10 + tt];
      ar += xrv[tt] * wrc - xiv[tt] * wic;
      ai += xrv[tt] * wic + xiv[tt] * wrc;
    }
    out[c] = fmaxf(ar, 0.f);
    out[10 + c] = fmaxf(ai, 0.f);
  }
  float4* yp = (float4*)(Y + (size_t)n * 20);
#pragma unroll
  for (int i = 0; i < 5; i++)
    yp[i] = make_float4(out[4 * i], out[4 * i + 1], out[4 * i + 2], out[4 * i + 3]);
  unsigned* yh = Yh + (size_t)n * 10;
#pragma unroll
  for (int i = 0; i < 10; i++) {
    half2v hv; hv.x = (_Float16)out[2 * i]; hv.y = (_Float16)out[2 * i + 1];
    yh[i] = *(unsigned*)&hv;
  }
}

// ---------------- Laplacian pass 1: T1 = Y - S(Y) ----------------
// R18 2-lane structure (h = real/imag half), 2-wide edge unroll.
// R21: gathers from fp16 Yh (20B/lane); own row + T1 output stay fp32;
// additionally writes fp16 T1h shadow for lap2cheb's gather.

__global__ __launch_bounds__(512) void k_lap1(const float* __restrict__ Y, const unsigned* __restrict__ Yh,
                                              const int2* __restrict__ ecsr,
                                              const int* __restrict__ rowstart, const int* __restrict__ cnt,
                                              float* __restrict__ T1, unsigned* __restrict__ T1h) {
  int gid = blockIdx.x * 512 + threadIdx.x;
  int n = gid >> 1, h = gid & 1;
  float acc[10];
#pragma unroll
  for (int j = 0; j < 10; j++) acc[j] = 0.f;
  int e0 = rowstart[n], ec = cnt[n];
  int i = 0;
  for (; i + 2 <= ec; i += 2) {
    int2 ra = ecsr[e0 + i];
    int2 rb = ecsr[e0 + i + 1];
    float wa = __int_as_float(ra.y), wb = __int_as_float(rb.y);
    const unsigned* pa = Yh + (size_t)ra.x * 10 + h * 5;
    const unsigned* pb = Yh + (size_t)rb.x * 10 + h * 5;
    unsigned ua0 = pa[0], ua1 = pa[1], ua2 = pa[2], ua3 = pa[3], ua4 = pa[4];
    unsigned ub0 = pb[0], ub1 = pb[1], ub2 = pb[2], ub3 = pb[3], ub4 = pb[4];
#pragma unroll
    for (int q = 0; q < 5; q++) {
      unsigned ua = (q == 0) ? ua0 : (q == 1) ? ua1 : (q == 2) ? ua2 : (q == 3) ? ua3 : ua4;
      half2v ha = *(half2v*)&ua;
      acc[2 * q]     += wa * (float)ha.x;
      acc[2 * q + 1] += wa * (float)ha.y;
    }
#pragma unroll
    for (int q = 0; q < 5; q++) {
      unsigned ub = (q == 0) ? ub0 : (q == 1) ? ub1 : (q == 2) ? ub2 : (q == 3) ? ub3 : ub4;
      half2v hb = *(half2v*)&ub;
      acc[2 * q]     += wb * (float)hb.x;
      acc[2 * q + 1] += wb * (float)hb.y;
    }
  }
  if (i < ec) {
    int2 rec = ecsr[e0 + i];
    float w = __int_as_float(rec.y);
    const unsigned* yp = Yh + (size_t)rec.x * 10 + h * 5;
#pragma unroll
    for (int q = 0; q < 5; q++) {
      unsigned u = yp[q];
      half2v hv = *(half2v*)&u;
      acc[2 * q]     += w * (float)hv.x;
      acc[2 * q + 1] += w * (float)hv.y;
    }
  }
  const float2* yn = (const float2*)(Y + (size_t)n * 20 + h * 10);
  float2* tp = (float2*)(T1 + (size_t)n * 20 + h * 10);
  unsigned* th = T1h + (size_t)n * 10 + h * 5;
#pragma unroll
  for (int q = 0; q < 5; q++) {
    float2 v = yn[q];
    float r0 = v.x - acc[2 * q], r1 = v.y - acc[2 * q + 1];
    tp[q] = make_float2(r0, r1);
    half2v hv; hv.x = (_Float16)r0; hv.y = (_Float16)r1;
    th[q] = *(unsigned*)&hv;
  }
}

// ---------------- Laplacian pass 2 + Chebyshev combine + ReLU ----------------
// Gathers from fp16 T1h; own rows (t0, t1) and combine stay fp32.

__global__ __launch_bounds__(512) void k_lap2cheb(const float* __restrict__ Y, const float* __restrict__ T1,
                                                  const unsigned* __restrict__ T1h,
                                                  const int2* __restrict__ ecsr,
                                                  const int* __restrict__ rowstart, const int* __restrict__ cnt,
                                                  const float* __restrict__ cw_g, const float* __restrict__ cb_g,
                                                  float* __restrict__ zr, float* __restrict__ zi) {
  __shared__ float cw[300], cb[10];
  int t = threadIdx.x;
  if (t < 300) cw[t] = cw_g[t];
  if (t < 10)  cb[t] = cb_g[t];
  __syncthreads();
  int gid = blockIdx.x * 512 + t;
  int n = gid >> 1, h = gid & 1;
  float acc[10];
#pragma unroll
  for (int j = 0; j < 10; j++) acc[j] = 0.f;
  int e0 = rowstart[n], ec = cnt[n];
  int i = 0;
  for (; i + 2 <= ec; i += 2) {
    int2 ra = ecsr[e0 + i];
    int2 rb = ecsr[e0 + i + 1];
    float wa = __int_as_float(ra.y), wb = __int_as_float(rb.y);
    const unsigned* pa = T1h + (size_t)ra.x * 10 + h * 5;
    const unsigned* pb = T1h + (size_t)rb.x * 10 + h * 5;
    unsigned ua0 = pa[0], ua1 = pa[1], ua2 = pa[2], ua3 = pa[3], ua4 = pa[4];
    unsigned ub0 = pb[0], ub1 = pb[1], ub2 = pb[2], ub3 = pb[3], ub4 = pb[4];
#pragma unroll
    for (int q = 0; q < 5; q++) {
      unsigned ua = (q == 0) ? ua0 : (q == 1) ? ua1 : (q == 2) ? ua2 : (q == 3) ? ua3 : ua4;
      half2v ha = *(half2v*)&ua;
      acc[2 * q]     += wa * (float)ha.x;
      acc[2 * q + 1] += wa * (float)ha.y;
    }
#pragma unroll
    for (int q = 0; q < 5; q++) {
      unsigned ub = (q == 0) ? ub0 : (q == 1) ? ub1 : (q == 2) ? ub2 : (q == 3) ? ub3 : ub4;
      half2v hb = *(half2v*)&ub;
      acc[2 * q]     += wb * (float)hb.x;
      acc[2 * q + 1] += wb * (float)hb.y;
    }
  }
  if (i < ec) {
    int2 rec = ecsr[e0 + i];
    float w = __int_as_float(rec.y);
    const unsigned* tp = T1h + (size_t)rec.x * 10 + h * 5;
#pragma unroll
    for (int q = 0; q < 5; q++) {
      unsigned u = tp[q];
      half2v hv = *(half2v*)&u;
      acc[2 * q]     += w * (float)hv.x;
      acc[2 * q + 1] += w * (float)hv.y;
    }
  }
  float t0[10], t1v[10], t2[10];
  const float2* yn = (const float2*)(Y + (size_t)n * 20 + h * 10);
  const float2* tn = (const float2*)(T1 + (size_t)n * 20 + h * 10);
#pragma unroll
  for (int q = 0; q < 5; q++) {
    float2 v = yn[q]; t0[2 * q] = v.x; t0[2 * q + 1] = v.y;
    float2 u = tn[q]; t1v[2 * q] = u.x; t1v[2 * q + 1] = u.y;
  }
#pragma unroll
  for (int j = 0; j < 10; j++) t2[j] = 2.f * (t1v[j] - acc[j]) - t0[j];

  float outv[10];
#pragma unroll
  for (int o = 0; o < 10; o++) outv[o] = h ? 0.f : cb[o];
#pragma unroll
  for (int j = 0; j < 10; j++) {
#pragma unroll
    for (int o = 0; o < 10; o++) {
      outv[o] += t0[j] * cw[j * 10 + o] + t1v[j] * cw[100 + j * 10 + o] + t2[j] * cw[200 + j * 10 + o];
    }
  }
  float2* zp = (float2*)((h ? zi : zr) + (size_t)n * 10);
#pragma unroll
  for (int q = 0; q < 5; q++)
    zp[q] = make_float2(fmaxf(outv[2 * q], 0.f), fmaxf(outv[2 * q + 1], 0.f));
}

// ---------------- fc1 complex GEMM: split-bf16 MFMA (R18, unchanged) ----------------

__device__ __forceinline__ unsigned cvtpk(float a, float b) {
  unsigned r;
  asm("v_cvt_pk_bf16_f32 %0, %1, %2" : "=v"(r) : "v"(a), "v"(b));
  return r;   // low16 = bf16(a), high16 = bf16(b)
}

#define LIDX(a, r, c) (((a) * 64 + (r)) * LSTR + (c))

__global__ __launch_bounds__(256) void k_fc1(const float* __restrict__ zr, const float* __restrict__ zi,
                                             const float* __restrict__ Wr, const float* __restrict__ Wi,
                                             float* __restrict__ pacc) {
  __shared__ unsigned short ls[8 * 64 * LSTR];   // 0 zrh,1 zrl,2 zih,3 zil,4 wrh,5 wrl,6 wih,7 wil
  int t = threadIdx.x;
  int hb = blockIdx.x;          // 0..7
  int kc = blockIdx.y;          // 0..NKC-1
  int H0 = hb * 64;
  int lane = t & 63, wv = t >> 6;
  int m = lane & 15, q = lane >> 4;

  int r0 = t >> 3, grp = t & 7;
  int colbase = kc * CHUNK + grp * 4;
  const float* pz  = zr + (size_t)r0 * K_ + colbase;
  const float* pzi = zi + (size_t)r0 * K_ + colbase;
  const float* pw  = Wr + (size_t)(H0 + r0) * K_ + colbase;
  const float* pwi = Wi + (size_t)(H0 + r0) * K_ + colbase;
  const size_t ROFF = (size_t)32 * K_;     // odd-p row offset (+32 rows)

  f32x4 p1[4], p2[4], p3[4], p4[4];
  f32x4 zero4 = {0.f, 0.f, 0.f, 0.f};
#pragma unroll
  for (int i = 0; i < 4; i++) { p1[i] = zero4; p2[i] = zero4; p3[i] = zero4; p4[i] = zero4; }

  float4 v[8];
#pragma unroll
  for (int p = 0; p < 8; p++) {
    const float* bases[4] = {pz, pzi, pw, pwi};
    v[p] = *(const float4*)(bases[p >> 1] + (p & 1) * ROFF);
  }

#pragma unroll 1
  for (int ks = 0; ks < KSTEPS; ks++) {
#pragma unroll
    for (int p = 0; p < 8; p++) {
      int arr = p >> 1;
      int row = r0 + (p & 1) * 32;
      float4 f = v[p];
      unsigned h01 = cvtpk(f.x, f.y);
      unsigned h23 = cvtpk(f.z, f.w);
      float l0 = f.x - __uint_as_float(h01 << 16);
      float l1 = f.y - __uint_as_float(h01 & 0xFFFF0000u);
      float l2 = f.z - __uint_as_float(h23 << 16);
      float l3 = f.w - __uint_as_float(h23 & 0xFFFF0000u);
      *(uint2*)&ls[LIDX(arr * 2,     row, grp * 4)] = make_uint2(h01, h23);
      *(uint2*)&ls[LIDX(arr * 2 + 1, row, grp * 4)] = make_uint2(cvtpk(l0, l1), cvtpk(l2, l3));
    }
    __syncthreads();
    if (ks + 1 < KSTEPS) {
      int koff = (ks + 1) * 32;
#pragma unroll
      for (int p = 0; p < 8; p++) {
        const float* bases[4] = {pz, pzi, pw, pwi};
        v[p] = *(const float4*)(bases[p >> 1] + (p & 1) * ROFF + koff);
      }
    }

    short8 bwrh = *(const short8*)&ls[LIDX(4, wv * 16 + m, q * 8)];
    short8 bwrl = *(const short8*)&ls[LIDX(5, wv * 16 + m, q * 8)];
    short8 bwih = *(const short8*)&ls[LIDX(6, wv * 16 + m, q * 8)];
    short8 bwil = *(const short8*)&ls[LIDX(7, wv * 16 + m, q * 8)];
#pragma unroll
    for (int mt = 0; mt < 4; mt++) {
      short8 azrh = *(const short8*)&ls[LIDX(0, mt * 16 + m, q * 8)];
      short8 azrl = *(const short8*)&ls[LIDX(1, mt * 16 + m, q * 8)];
      short8 azih = *(const short8*)&ls[LIDX(2, mt * 16 + m, q * 8)];
      short8 azil = *(const short8*)&ls[LIDX(3, mt * 16 + m, q * 8)];
      p1[mt] = __builtin_amdgcn_mfma_f32_16x16x32_bf16(azrh, bwrh, p1[mt], 0, 0, 0);
      p2[mt] = __builtin_amdgcn_mfma_f32_16x16x32_bf16(azih, bwih, p2[mt], 0, 0, 0);
      p3[mt] = __builtin_amdgcn_mfma_f32_16x16x32_bf16(azrh, bwih, p3[mt], 0, 0, 0);
      p4[mt] = __builtin_amdgcn_mfma_f32_16x16x32_bf16(azih, bwrh, p4[mt], 0, 0, 0);
      p1[mt] = __builtin_amdgcn_mfma_f32_16x16x32_bf16(azrh, bwrl, p1[mt], 0, 0, 0);
      p2[mt] = __builtin_amdgcn_mfma_f32_16x16x32_bf16(azih, bwil, p2[mt], 0, 0, 0);
      p3[mt] = __builtin_amdgcn_mfma_f32_16x16x32_bf16(azrh, bwil, p3[mt], 0, 0, 0);
      p4[mt] = __builtin_amdgcn_mfma_f32_16x16x32_bf16(azih, bwrl, p4[mt], 0, 0, 0);
      p1[mt] = __builtin_amdgcn_mfma_f32_16x16x32_bf16(azrl, bwrh, p1[mt], 0, 0, 0);
      p2[mt] = __builtin_amdgcn_mfma_f32_16x16x32_bf16(azil, bwih, p2[mt], 0, 0, 0);
      p3[mt] = __builtin_amdgcn_mfma_f32_16x16x32_bf16(azrl, bwih, p3[mt], 0, 0, 0);
      p4[mt] = __builtin_amdgcn_mfma_f32_16x16x32_bf16(azil, bwrh, p4[mt], 0, 0, 0);
    }
    __syncthreads();
  }

#pragma unroll
  for (int mt = 0; mt < 4; mt++) {
#pragma unroll
    for (int i = 0; i < 4; i++) {
      int b = mt * 16 + q * 4 + i;
      int h = H0 + wv * 16 + m;
      *(float2*)&pacc[(((size_t)kc * 64 + b) * 512 + h) * 2] =
          make_float2(p1[mt][i] - p2[mt][i], p3[mt][i] + p4[mt][i]);
    }
  }
}

// ---------------- head, split for parallelism (R11) ----------------

__global__ __launch_bounds__(256) void k_red(const float* __restrict__ pacc, float* __restrict__ upart) {
  int b = blockIdx.x;            // 0..63
  int c = blockIdx.y;            // 0..1
  int s = blockIdx.z;            // 0..3 (kc quarter)
  int t = threadIdx.x;
  int h = c * 256 + t;           // 0..511
  float sr = 0.f, si = 0.f;
  int kc0 = s * (NKC / 4);
#pragma unroll 4
  for (int kc = kc0; kc < kc0 + NKC / 4; kc++) {
    float2 v = *(const float2*)&pacc[(((size_t)kc * 64 + b) * 512 + h) * 2];
    sr += v.x; si += v.y;
  }
  float* up = upart + ((size_t)s * 64 + b) * 1024;
  up[h] = sr;
  up[512 + h] = si;
}

__global__ __launch_bounds__(320) void k_head2(const float* __restrict__ upart,
                                               const float* __restrict__ br, const float* __restrict__ bi,
                                               const float* __restrict__ actor_w, const float* __restrict__ actor_b,
                                               const float* __restrict__ critic_w, const float* __restrict__ critic_b,
                                               float* __restrict__ out) {
  __shared__ float cs[1024];
  int b = blockIdx.x, t = threadIdx.x;
  for (int k = t; k < 1024; k += 320) {
    float s = 0.f;
#pragma unroll
    for (int s4 = 0; s4 < 4; s4++) s += upart[((size_t)s4 * 64 + b) * 1024 + k];
    float bias = (k < 512) ? br[k] : bi[k - 512];
    cs[k] = fmaxf(s + bias, 0.f);
  }
  __syncthreads();
  if (t < 264) {                               // 33 outputs x 8 lanes
    int o = t >> 3, r = t & 7;
    const float* w = (o < 32) ? (actor_w + o * 1024) : critic_w;
    float acc = 0.f;
    const int j0 = r * 128;
#pragma unroll 8
    for (int j = 0; j < 128; j++) acc += cs[j0 + j] * w[j0 + j];
    acc += __shfl_down(acc, 4, 8);
    acc += __shfl_down(acc, 2, 8);
    acc += __shfl_down(acc, 1, 8);
    if (r == 0) {
      acc += (o < 32) ? actor_b[o] : critic_b[0];
      if (o < 32) out[b * 32 + o] = acc;
      else        out[2048 + b] = acc;
    }
  }
}

// ---------------- launch ----------------

extern "C" void kernel_launch(void* const* d_in, const int* in_sizes, int n_in,
                              void* d_out, int out_size, void* d_ws, size_t ws_size,
                              hipStream_t stream) {
  const float* xr   = (const float*)d_in[0];
  const float* xi   = (const float*)d_in[1];
  const float* ew   = (const float*)d_in[2];
  const float* c1wr = (const float*)d_in[3];
  const float* c1wi = (const float*)d_in[4];
  const float* c1br = (const float*)d_in[5];
  const float* c1bi = (const float*)d_in[6];
  const float* chw  = (const float*)d_in[7];
  const float* chb  = (const float*)d_in[8];
  const float* f1wr = (const float*)d_in[9];
  const float* f1wi = (const float*)d_in[10];
  const float* f1br = (const float*)d_in[11];
  const float* f1bi = (const float*)d_in[12];
  const float* cw   = (const float*)d_in[13];
  const float* cb   = (const float*)d_in[14];
  const float* aw   = (const float*)d_in[15];
  const float* ab   = (const float*)d_in[16];
  const int*   ei   = (const int*)d_in[17];
  float* out = (float*)d_out;

  char* ws = (char*)d_ws;
  size_t off = 0;
  auto alloc = [&](size_t bytes) { char* p = ws + off; off += (bytes + 255) & ~(size_t)255; return p; };
  int*   cnt      = (int*)  alloc((size_t)NN_ * 4);
  int*   rowstart = (int*)  alloc((size_t)NN_ * 4);
  float* dinv     = (float*)alloc((size_t)NN_ * 4);
  int*   btot     = (int*)  alloc((size_t)NB * 4);
  int*   bstart   = (int*)  alloc((size_t)(NB + 1) * 4);
  float* zr       = (float*)alloc((size_t)NN_ * 10 * 4);
  float* zi       = (float*)alloc((size_t)NN_ * 10 * 4);
  int2*  ecsr     = (int2*) alloc((size_t)E_ * 8);    // born at k_p2; dead after lap2cheb
  float* Y        = (float*)alloc((size_t)NN_ * 20 * 4);   // born at conv1
  float* T1       = (float*)alloc((size_t)NN_ * 20 * 4);   // born at lap1 (contiguous after Y)
  unsigned* T1h   = (unsigned*)alloc((size_t)NN_ * 10 * 4); // fp16 shadow of T1 (5.25 MB)
  // blockhist (2 MB, dead after p1scat) aliases ecsr head (ecsr born at k_p2)
  int* blockhist = (int*)ecsr;
  // recA (16 MB), dead after k_p2, aliases Y+T1 (contiguous 21 MB)
  int2* recA = (int2*)Y;
  // Yh fp16 shadow (5.25 MB, live conv1..lap1) aliases zr (born at lap2cheb)
  unsigned* Yh = (unsigned*)zr;
  // pacc (33.5 MB, born at fc1) aliases ecsr+Y+T1 (37.8 MB, all dead by then)
  float* pacc = (float*)ecsr;
  // upart (1 MB, born at k_red) aliases zr... zr is LIVE during k_red (fc1 done
  // reading it, but keep separate to be safe): alias Y region instead? pacc
  // occupies it. Use T1h (dead after lap2cheb) for upart (1 MB < 5.25 MB).
  float* upart = (float*)T1h;

  k_p1hist<<<P1B, 256, 0, stream>>>(ei, blockhist);
  k_p1scanA<<<NB, 256, 0, stream>>>(blockhist, btot);
  k_p1scanB<<<1, 256, 0, stream>>>(btot, bstart);
  k_p1scat<<<P1B, 256, 0, stream>>>(ei, ew, blockhist, bstart, recA);
  k_p2<<<NB, 256, 0, stream>>>(recA, bstart, cnt, rowstart, dinv, ecsr);
  k_wfix<<<E_ / 256, 256, 0, stream>>>(ecsr, dinv);
  k_conv1<<<NN_ / 256, 256, 0, stream>>>(xr, xi, c1wr, c1wi, c1br, c1bi, Y, Yh);
  k_lap1<<<NN_ * 2 / 512, 512, 0, stream>>>(Y, Yh, ecsr, rowstart, cnt, T1, T1h);
  k_lap2cheb<<<NN_ * 2 / 512, 512, 0, stream>>>(Y, T1, T1h, ecsr, rowstart, cnt, chw, chb, zr, zi);
  k_fc1<<<dim3(8, NKC), 256, 0, stream>>>(zr, zi, f1wr, f1wi, pacc);
  k_red<<<dim3(64, 2, 4), 256, 0, stream>>>(pacc, upart);
  k_head2<<<B_, 320, 0, stream>>>(upart, f1br, f1bi, aw, ab, cw, cb, out);
}

// Round 12
// 339.220 us; speedup vs baseline: 1.2785x; 1.0039x over previous
//
#include <hip/hip_runtime.h>

#define NN_ 131072
#define E_  2097152
#define B_  64
#define K_  20480
#define H_  512
#define EPS_ 1e-6f
#define DEGSCALE 4194304.0f      // 2^22
#define DEGINV   (1.0f / 4194304.0f)
#define NKC 128                  // fc1 K-split chunks
#define CHUNK 160                // K_ / NKC
#define KSTEPS 5                 // CHUNK / 32 (MFMA k=32 per step)
#define LSTR 40                  // fc1 LDS row stride in bf16 elems
#define NB 1024                  // CSR buckets
#define RPB 128                  // rows per bucket (NN/NB)
#define EB 4096                  // edges per p1 block (R15: 4096 for LDS-staged writeout)
#define P1B (E_ / EB)            // 512 p1 blocks
#define EPT (EB / 256)           // 16 edges per thread

typedef __attribute__((ext_vector_type(8))) short short8;   // 8 bf16 (4 VGPRs)
typedef __attribute__((ext_vector_type(4))) float f32x4;    // MFMA accumulator
typedef __attribute__((ext_vector_type(2))) _Float16 half2v; // 2 fp16 in 4B

// ---------------- graph preprocessing: bucket-sort CSR, ZERO global atomics ----
// R10: global atomics write through to HBM. 2-level bucket sort.
// R13: per-row edges sorted by column CHUNK (col>>14, 8 chunks) -> lap gathers
// sweep the column space roughly in lockstep, active band mostly L2-resident.
// R15: p1scat LDS-staged bucket-ordered writeout + packed recA.
// R19/R20 falsified the lap latency theory: BW pinned ~3.3 TB/s at occ
// 19/35/76% -> random-64B-line ceiling. R21: fp16 gather shadows (Yh/T1h)
// halve gathered bytes -> laps ~33us (absmax 1.2e-4, passes).
// R22: fc1 was register-bound: 76 VGPR + 64 AGPR acc = 140 -> 2 waves/SIMD
// (occ 19.5%). Fold p1-p2/p3+p4 into p_re/p_im by negating zi A-fragments
// in registers (4 v_xor per short8, exact) -> 32 AGPR, ~112 combined ->
// 4 waves/SIMD, 16 waves/CU.

__global__ __launch_bounds__(256) void k_p1hist(const int* __restrict__ ei, int* __restrict__ blockhist) {
  __shared__ int h[NB];
  int t = threadIdx.x, blk = blockIdx.x;
  for (int i = t; i < NB; i += 256) h[i] = 0;
  __syncthreads();
  int e0 = blk * EB;
#pragma unroll
  for (int i = 0; i < EPT; i++) {
    int r = ei[e0 + i * 256 + t];
    atomicAdd(&h[r >> 7], 1);
  }
  __syncthreads();
  for (int i = t; i < NB; i += 256) blockhist[blk * NB + i] = h[i];
}

// per-bucket exclusive scan over the P1B block counts (in place) + bucket totals
__global__ __launch_bounds__(256) void k_p1scanA(int* __restrict__ blockhist, int* __restrict__ btot) {
  __shared__ int s[256];
  int t = threadIdx.x, b = blockIdx.x;
  int v[P1B / 256], sum = 0;
#pragma unroll
  for (int j = 0; j < P1B / 256; j++) { v[j] = blockhist[((P1B / 256) * t + j) * NB + b]; sum += v[j]; }
  s[t] = sum;
  __syncthreads();
  for (int off = 1; off < 256; off <<= 1) {
    int x = (t >= off) ? s[t - off] : 0;
    __syncthreads();
    s[t] += x;
    __syncthreads();
  }
  int o = s[t] - sum;
#pragma unroll
  for (int j = 0; j < P1B / 256; j++) { blockhist[((P1B / 256) * t + j) * NB + b] = o; o += v[j]; }
  if (t == 0) btot[b] = s[255];
}

// exclusive scan of 1024 bucket totals -> bstart[0..NB], bstart[NB]=E
__global__ __launch_bounds__(256) void k_p1scanB(const int* __restrict__ btot, int* __restrict__ bstart) {
  __shared__ int s[256];
  int t = threadIdx.x;
  int v[4], sum = 0;
#pragma unroll
  for (int j = 0; j < 4; j++) { v[j] = btot[4 * t + j]; sum += v[j]; }
  s[t] = sum;
  __syncthreads();
  for (int off = 1; off < 256; off <<= 1) {
    int x = (t >= off) ? s[t - off] : 0;
    __syncthreads();
    s[t] += x;
    __syncthreads();
  }
  int o = s[t] - sum;
#pragma unroll
  for (int j = 0; j < 4; j++) { bstart[4 * t + j] = o; o += v[j]; }
  if (t == 0) bstart[NB] = s[255];
}

// R15: LDS-staged bucket-ordered scatter. Records packed (col | lr<<17, w).
__global__ __launch_bounds__(256) void k_p1scat(const int* __restrict__ ei, const float* __restrict__ ew,
                                                const int* __restrict__ blockhist, const int* __restrict__ bstart,
                                                int2* __restrict__ recA) {
  __shared__ int loff[NB], run[NB], base2[NB], sc[256];
  __shared__ int2 Ast[EB];                 // 32 KB bucket-sorted staging
  __shared__ unsigned short bst[EB];       // bucket id of staged record
  int t = threadIdx.x, blk = blockIdx.x;
  for (int i = t; i < NB; i += 256) {
    run[i] = 0;
    base2[i] = bstart[i] + blockhist[blk * NB + i];
  }
  __syncthreads();
  int e0 = blk * EB;
  int rv[EPT], cv[EPT];
  float wv[EPT];
#pragma unroll
  for (int i = 0; i < EPT; i++) {
    int e = e0 + i * 256 + t;
    rv[i] = ei[e];
    cv[i] = ei[E_ + e];
    wv[i] = ew[e];
    atomicAdd(&run[rv[i] >> 7], 1);        // local histogram
  }
  __syncthreads();
  // exclusive scan of the 1024-entry local histogram
  int v[4], sum = 0;
#pragma unroll
  for (int j = 0; j < 4; j++) { v[j] = run[4 * t + j]; sum += v[j]; }
  sc[t] = sum;
  __syncthreads();
  for (int off = 1; off < 256; off <<= 1) {
    int x = (t >= off) ? sc[t - off] : 0;
    __syncthreads();
    sc[t] += x;
    __syncthreads();
  }
  int o = sc[t] - sum;
#pragma unroll
  for (int j = 0; j < 4; j++) { loff[4 * t + j] = o; o += v[j]; }
  __syncthreads();
  for (int i = t; i < NB; i += 256) run[i] = 0;
  __syncthreads();
  // scatter into LDS in bucket order
#pragma unroll
  for (int i = 0; i < EPT; i++) {
    int bkt = rv[i] >> 7;
    int lpos = loff[bkt] + atomicAdd(&run[bkt], 1);
    Ast[lpos] = make_int2(cv[i] | ((rv[i] & 127) << 17), __float_as_int(wv[i]));
    bst[lpos] = (unsigned short)bkt;
  }
  __syncthreads();
  // linear writeout: consecutive i within a bucket -> consecutive global pos
  for (int i = t; i < EB; i += 256) {
    int bkt = bst[i];
    recA[base2[bkt] + (i - loff[bkt])] = Ast[i];
  }
}

// per-bucket: cell = localrow*8 + colchunk. Count cells + Q22 deg -> dinv /
// cnt / rowstart; scatter chunk-sorted ecsr (w = ew*dinv[r]).
__global__ __launch_bounds__(256) void k_p2(const int2* __restrict__ recA,
                                            const int* __restrict__ bstart,
                                            int* __restrict__ cnt_g, int* __restrict__ rowstart,
                                            float* __restrict__ dinv, int2* __restrict__ ecsr) {
  __shared__ int cnt_s[1024], excl_s[1024], run_s[1024], sc[256];
  __shared__ unsigned deg_s[RPB];
  __shared__ float dl[RPB];
  int t = threadIdx.x, b = blockIdx.x;
  int b0 = bstart[b], nE = bstart[b + 1] - b0;
  for (int j = t; j < 1024; j += 256) { cnt_s[j] = 0; run_s[j] = 0; }
  if (t < RPB) deg_s[t] = 0;
  __syncthreads();
  for (int i = t; i < nE; i += 256) {
    int2 ra = recA[b0 + i];
    int lr = ((unsigned)ra.x >> 17) & 127;
    int col = ra.x & 131071;
    float w = __int_as_float(ra.y);
    atomicAdd(&cnt_s[lr * 8 + ((unsigned)col >> 14)], 1);
    atomicAdd(&deg_s[lr], (unsigned)(w * DEGSCALE + 0.5f));
  }
  __syncthreads();
  int v[4], sum = 0;
#pragma unroll
  for (int j = 0; j < 4; j++) { v[j] = cnt_s[4 * t + j]; sum += v[j]; }
  sc[t] = sum;
  __syncthreads();
  for (int off = 1; off < 256; off <<= 1) {
    int x = (t >= off) ? sc[t - off] : 0;
    __syncthreads();
    sc[t] += x;
    __syncthreads();
  }
  int o = sc[t] - sum;
#pragma unroll
  for (int j = 0; j < 4; j++) { excl_s[4 * t + j] = o; o += v[j]; }
  __syncthreads();
  if (t < RPB) {
    int row = b * RPB + t;
    int e0r = excl_s[t * 8];
    int e1r = (t < RPB - 1) ? excl_s[t * 8 + 8] : nE;
    rowstart[row] = b0 + e0r;
    cnt_g[row] = e1r - e0r;
    float d = (float)deg_s[t] * DEGINV;
    float dv = (d > 0.f) ? rsqrtf(d + EPS_) : 0.f;
    dl[t] = dv;
    dinv[row] = dv;
  }
  __syncthreads();
  for (int i = t; i < nE; i += 256) {
    int2 ra = recA[b0 + i];
    int lr = ((unsigned)ra.x >> 17) & 127;
    int col = ra.x & 131071;
    int cell = lr * 8 + ((unsigned)col >> 14);
    int pos = excl_s[cell] + atomicAdd(&run_s[cell], 1);
    float wp = __int_as_float(ra.y) * dl[lr];
    ecsr[b0 + pos] = make_int2(col, __float_as_int(wp));
  }
}

// finalize w *= dinv[col]  (keeps lap kernels unchanged)
__global__ __launch_bounds__(256) void k_wfix(int2* __restrict__ ecsr, const float* __restrict__ dinv) {
  int e = blockIdx.x * 256 + threadIdx.x;
  if (e >= E_) return;
  int2 r = ecsr[e];
  r.y = __float_as_int(__int_as_float(r.y) * dinv[r.x]);
  ecsr[e] = r;
}

// ---------------- conv1 (complex 1x1 conv + ReLU) ----------------
// Y layout: [NN][20] fp32 (0..9 real, 10..19 imag) + Yh fp16 shadow [NN][20]h.

__global__ __launch_bounds__(256) void k_conv1(const float* __restrict__ xr, const float* __restrict__ xi,
                                               const float* __restrict__ wr_g, const float* __restrict__ wi_g,
                                               const float* __restrict__ br_g, const float* __restrict__ bi_g,
                                               float* __restrict__ Y, unsigned* __restrict__ Yh) {
  __shared__ float wr[100], wi[100], br[10], bi[10];
  int t = threadIdx.x;
  if (t < 100) { wr[t] = wr_g[t]; wi[t] = wi_g[t]; }
  if (t < 10)  { br[t] = br_g[t]; bi[t] = bi_g[t]; }
  __syncthreads();
  int n = blockIdx.x * 256 + t;
  float xrv[10], xiv[10];
  const float2* a = (const float2*)(xr + (size_t)n * 10);
  const float2* b2 = (const float2*)(xi + (size_t)n * 10);
#pragma unroll
  for (int i = 0; i < 5; i++) {
    float2 v = a[i];  xrv[2 * i] = v.x; xrv[2 * i + 1] = v.y;
    float2 u = b2[i]; xiv[2 * i] = u.x; xiv[2 * i + 1] = u.y;
  }
  float out[20];
#pragma unroll
  for (int c = 0; c < 10; c++) {
    float ar = br[c], ai = bi[c];
#pragma unroll
    for (int tt = 0; tt < 10; tt++) {
      float wrc = wr[c * 10 + tt], wic = wi[c * 10 + tt];
      ar += xrv[tt] * wrc - xiv[tt] * wic;
      ai += xrv[tt] * wic + xiv[tt] * wrc;
    }
    out[c] = fmaxf(ar, 0.f);
    out[10 + c] = fmaxf(ai, 0.f);
  }
  float4* yp = (float4*)(Y + (size_t)n * 20);
#pragma unroll
  for (int i = 0; i < 5; i++)
    yp[i] = make_float4(out[4 * i], out[4 * i + 1], out[4 * i + 2], out[4 * i + 3]);
  unsigned* yh = Yh + (size_t)n * 10;
#pragma unroll
  for (int i = 0; i < 10; i++) {
    half2v hv; hv.x = (_Float16)out[2 * i]; hv.y = (_Float16)out[2 * i + 1];
    yh[i] = *(unsigned*)&hv;
  }
}

// ---------------- Laplacian pass 1: T1 = Y - S(Y) ----------------
// R18 2-lane structure (h = real/imag half), 2-wide edge unroll.
// R21: gathers from fp16 Yh (20B/lane); own row + T1 output stay fp32;
// additionally writes fp16 T1h shadow for lap2cheb's gather.

__global__ __launch_bounds__(512) void k_lap1(const float* __restrict__ Y, const unsigned* __restrict__ Yh,
                                              const int2* __restrict__ ecsr,
                                              const int* __restrict__ rowstart, const int* __restrict__ cnt,
                                              float* __restrict__ T1, unsigned* __restrict__ T1h) {
  int gid = blockIdx.x * 512 + threadIdx.x;
  int n = gid >> 1, h = gid & 1;
  float acc[10];
#pragma unroll
  for (int j = 0; j < 10; j++) acc[j] = 0.f;
  int e0 = rowstart[n], ec = cnt[n];
  int i = 0;
  for (; i + 2 <= ec; i += 2) {
    int2 ra = ecsr[e0 + i];
    int2 rb = ecsr[e0 + i + 1];
    float wa = __int_as_float(ra.y), wb = __int_as_float(rb.y);
    const unsigned* pa = Yh + (size_t)ra.x * 10 + h * 5;
    const unsigned* pb = Yh + (size_t)rb.x * 10 + h * 5;
    unsigned ua0 = pa[0], ua1 = pa[1], ua2 = pa[2], ua3 = pa[3], ua4 = pa[4];
    unsigned ub0 = pb[0], ub1 = pb[1], ub2 = pb[2], ub3 = pb[3], ub4 = pb[4];
#pragma unroll
    for (int q = 0; q < 5; q++) {
      unsigned ua = (q == 0) ? ua0 : (q == 1) ? ua1 : (q == 2) ? ua2 : (q == 3) ? ua3 : ua4;
      half2v ha = *(half2v*)&ua;
      acc[2 * q]     += wa * (float)ha.x;
      acc[2 * q + 1] += wa * (float)ha.y;
    }
#pragma unroll
    for (int q = 0; q < 5; q++) {
      unsigned ub = (q == 0) ? ub0 : (q == 1) ? ub1 : (q == 2) ? ub2 : (q == 3) ? ub3 : ub4;
      half2v hb = *(half2v*)&ub;
      acc[2 * q]     += wb * (float)hb.x;
      acc[2 * q + 1] += wb * (float)hb.y;
    }
  }
  if (i < ec) {
    int2 rec = ecsr[e0 + i];
    float w = __int_as_float(rec.y);
    const unsigned* yp = Yh + (size_t)rec.x * 10 + h * 5;
#pragma unroll
    for (int q = 0; q < 5; q++) {
      unsigned u = yp[q];
      half2v hv = *(half2v*)&u;
      acc[2 * q]     += w * (float)hv.x;
      acc[2 * q + 1] += w * (float)hv.y;
    }
  }
  const float2* yn = (const float2*)(Y + (size_t)n * 20 + h * 10);
  float2* tp = (float2*)(T1 + (size_t)n * 20 + h * 10);
  unsigned* th = T1h + (size_t)n * 10 + h * 5;
#pragma unroll
  for (int q = 0; q < 5; q++) {
    float2 v = yn[q];
    float r0 = v.x - acc[2 * q], r1 = v.y - acc[2 * q + 1];
    tp[q] = make_float2(r0, r1);
    half2v hv; hv.x = (_Float16)r0; hv.y = (_Float16)r1;
    th[q] = *(unsigned*)&hv;
  }
}

// ---------------- Laplacian pass 2 + Chebyshev combine + ReLU ----------------
// Gathers from fp16 T1h; own rows (t0, t1) and combine stay fp32.

__global__ __launch_bounds__(512) void k_lap2cheb(const float* __restrict__ Y, const float* __restrict__ T1,
                                                  const unsigned* __restrict__ T1h,
                                                  const int2* __restrict__ ecsr,
                                                  const int* __restrict__ rowstart, const int* __restrict__ cnt,
                                                  const float* __restrict__ cw_g, const float* __restrict__ cb_g,
                                                  float* __restrict__ zr, float* __restrict__ zi) {
  __shared__ float cw[300], cb[10];
  int t = threadIdx.x;
  if (t < 300) cw[t] = cw_g[t];
  if (t < 10)  cb[t] = cb_g[t];
  __syncthreads();
  int gid = blockIdx.x * 512 + t;
  int n = gid >> 1, h = gid & 1;
  float acc[10];
#pragma unroll
  for (int j = 0; j < 10; j++) acc[j] = 0.f;
  int e0 = rowstart[n], ec = cnt[n];
  int i = 0;
  for (; i + 2 <= ec; i += 2) {
    int2 ra = ecsr[e0 + i];
    int2 rb = ecsr[e0 + i + 1];
    float wa = __int_as_float(ra.y), wb = __int_as_float(rb.y);
    const unsigned* pa = T1h + (size_t)ra.x * 10 + h * 5;
    const unsigned* pb = T1h + (size_t)rb.x * 10 + h * 5;
    unsigned ua0 = pa[0], ua1 = pa[1], ua2 = pa[2], ua3 = pa[3], ua4 = pa[4];
    unsigned ub0 = pb[0], ub1 = pb[1], ub2 = pb[2], ub3 = pb[3], ub4 = pb[4];
#pragma unroll
    for (int q = 0; q < 5; q++) {
      unsigned ua = (q == 0) ? ua0 : (q == 1) ? ua1 : (q == 2) ? ua2 : (q == 3) ? ua3 : ua4;
      half2v ha = *(half2v*)&ua;
      acc[2 * q]     += wa * (float)ha.x;
      acc[2 * q + 1] += wa * (float)ha.y;
    }
#pragma unroll
    for (int q = 0; q < 5; q++) {
      unsigned ub = (q == 0) ? ub0 : (q == 1) ? ub1 : (q == 2) ? ub2 : (q == 3) ? ub3 : ub4;
      half2v hb = *(half2v*)&ub;
      acc[2 * q]     += wb * (float)hb.x;
      acc[2 * q + 1] += wb * (float)hb.y;
    }
  }
  if (i < ec) {
    int2 rec = ecsr[e0 + i];
    float w = __int_as_float(rec.y);
    const unsigned* tp = T1h + (size_t)rec.x * 10 + h * 5;
#pragma unroll
    for (int q = 0; q < 5; q++) {
      unsigned u = tp[q];
      half2v hv = *(half2v*)&u;
      acc[2 * q]     += w * (float)hv.x;
      acc[2 * q + 1] += w * (float)hv.y;
    }
  }
  float t0[10], t1v[10], t2[10];
  const float2* yn = (const float2*)(Y + (size_t)n * 20 + h * 10);
  const float2* tn = (const float2*)(T1 + (size_t)n * 20 + h * 10);
#pragma unroll
  for (int q = 0; q < 5; q++) {
    float2 v = yn[q]; t0[2 * q] = v.x; t0[2 * q + 1] = v.y;
    float2 u = tn[q]; t1v[2 * q] = u.x; t1v[2 * q + 1] = u.y;
  }
#pragma unroll
  for (int j = 0; j < 10; j++) t2[j] = 2.f * (t1v[j] - acc[j]) - t0[j];

  float outv[10];
#pragma unroll
  for (int o = 0; o < 10; o++) outv[o] = h ? 0.f : cb[o];
#pragma unroll
  for (int j = 0; j < 10; j++) {
#pragma unroll
    for (int o = 0; o < 10; o++) {
      outv[o] += t0[j] * cw[j * 10 + o] + t1v[j] * cw[100 + j * 10 + o] + t2[j] * cw[200 + j * 10 + o];
    }
  }
  float2* zp = (float2*)((h ? zi : zr) + (size_t)n * 10);
#pragma unroll
  for (int q = 0; q < 5; q++)
    zp[q] = make_float2(fmaxf(outv[2 * q], 0.f), fmaxf(outv[2 * q + 1], 0.f));
}

// ---------------- fc1 complex GEMM: split-bf16 MFMA ----------------
// R18: cvtpk convert + issue-early prefetch. R22: folded accumulators —
// negate zi fragments in registers (bf16 sign xor, exact) so re/im each
// accumulate directly: 32 AGPR instead of 64 -> 4 waves/SIMD.

__device__ __forceinline__ unsigned cvtpk(float a, float b) {
  unsigned r;
  asm("v_cvt_pk_bf16_f32 %0, %1, %2" : "=v"(r) : "v"(a), "v"(b));
  return r;   // low16 = bf16(a), high16 = bf16(b)
}

__device__ __forceinline__ short8 negbf16x8(short8 a) {
  union { short8 s; unsigned u[4]; } x;
  x.s = a;
#pragma unroll
  for (int j = 0; j < 4; j++) x.u[j] ^= 0x80008000u;
  return x.s;
}

#define LIDX(a, r, c) (((a) * 64 + (r)) * LSTR + (c))

__global__ __launch_bounds__(256) void k_fc1(const float* __restrict__ zr, const float* __restrict__ zi,
                                             const float* __restrict__ Wr, const float* __restrict__ Wi,
                                             float* __restrict__ pacc) {
  __shared__ unsigned short ls[8 * 64 * LSTR];   // 0 zrh,1 zrl,2 zih,3 zil,4 wrh,5 wrl,6 wih,7 wil
  int t = threadIdx.x;
  int hb = blockIdx.x;          // 0..7
  int kc = blockIdx.y;          // 0..NKC-1
  int H0 = hb * 64;
  int lane = t & 63, wv = t >> 6;
  int m = lane & 15, q = lane >> 4;

  int r0 = t >> 3, grp = t & 7;
  int colbase = kc * CHUNK + grp * 4;
  const float* pz  = zr + (size_t)r0 * K_ + colbase;
  const float* pzi = zi + (size_t)r0 * K_ + colbase;
  const float* pw  = Wr + (size_t)(H0 + r0) * K_ + colbase;
  const float* pwi = Wi + (size_t)(H0 + r0) * K_ + colbase;
  const size_t ROFF = (size_t)32 * K_;     // odd-p row offset (+32 rows)

  f32x4 pre[4], pim[4];
  f32x4 zero4 = {0.f, 0.f, 0.f, 0.f};
#pragma unroll
  for (int i = 0; i < 4; i++) { pre[i] = zero4; pim[i] = zero4; }

  float4 v[8];
#pragma unroll
  for (int p = 0; p < 8; p++) {
    const float* bases[4] = {pz, pzi, pw, pwi};
    v[p] = *(const float4*)(bases[p >> 1] + (p & 1) * ROFF);
  }

#pragma unroll 1
  for (int ks = 0; ks < KSTEPS; ks++) {
#pragma unroll
    for (int p = 0; p < 8; p++) {
      int arr = p >> 1;
      int row = r0 + (p & 1) * 32;
      float4 f = v[p];
      unsigned h01 = cvtpk(f.x, f.y);
      unsigned h23 = cvtpk(f.z, f.w);
      float l0 = f.x - __uint_as_float(h01 << 16);
      float l1 = f.y - __uint_as_float(h01 & 0xFFFF0000u);
      float l2 = f.z - __uint_as_float(h23 << 16);
      float l3 = f.w - __uint_as_float(h23 & 0xFFFF0000u);
      *(uint2*)&ls[LIDX(arr * 2,     row, grp * 4)] = make_uint2(h01, h23);
      *(uint2*)&ls[LIDX(arr * 2 + 1, row, grp * 4)] = make_uint2(cvtpk(l0, l1), cvtpk(l2, l3));
    }
    __syncthreads();
    if (ks + 1 < KSTEPS) {
      int koff = (ks + 1) * 32;
#pragma unroll
      for (int p = 0; p < 8; p++) {
        const float* bases[4] = {pz, pzi, pw, pwi};
        v[p] = *(const float4*)(bases[p >> 1] + (p & 1) * ROFF + koff);
      }
    }

    short8 bwrh = *(const short8*)&ls[LIDX(4, wv * 16 + m, q * 8)];
    short8 bwrl = *(const short8*)&ls[LIDX(5, wv * 16 + m, q * 8)];
    short8 bwih = *(const short8*)&ls[LIDX(6, wv * 16 + m, q * 8)];
    short8 bwil = *(const short8*)&ls[LIDX(7, wv * 16 + m, q * 8)];
#pragma unroll
    for (int mt = 0; mt < 4; mt++) {
      short8 azrh = *(const short8*)&ls[LIDX(0, mt * 16 + m, q * 8)];
      short8 azrl = *(const short8*)&ls[LIDX(1, mt * 16 + m, q * 8)];
      short8 azih = *(const short8*)&ls[LIDX(2, mt * 16 + m, q * 8)];
      short8 azil = *(const short8*)&ls[LIDX(3, mt * 16 + m, q * 8)];
      short8 nzih = negbf16x8(azih);
      short8 nzil = negbf16x8(azil);
      // re = zr*Wr - zi*Wi  (hi/lo split; -zi via sign-flip, exact)
      pre[mt] = __builtin_amdgcn_mfma_f32_16x16x32_bf16(azrh, bwrh, pre[mt], 0, 0, 0);
      pre[mt] = __builtin_amdgcn_mfma_f32_16x16x32_bf16(nzih, bwih, pre[mt], 0, 0, 0);
      pre[mt] = __builtin_amdgcn_mfma_f32_16x16x32_bf16(azrh, bwrl, pre[mt], 0, 0, 0);
      pre[mt] = __builtin_amdgcn_mfma_f32_16x16x32_bf16(nzih, bwil, pre[mt], 0, 0, 0);
      pre[mt] = __builtin_amdgcn_mfma_f32_16x16x32_bf16(azrl, bwrh, pre[mt], 0, 0, 0);
      pre[mt] = __builtin_amdgcn_mfma_f32_16x16x32_bf16(nzil, bwih, pre[mt], 0, 0, 0);
      // im = zr*Wi + zi*Wr
      pim[mt] = __builtin_amdgcn_mfma_f32_16x16x32_bf16(azrh, bwih, pim[mt], 0, 0, 0);
      pim[mt] = __builtin_amdgcn_mfma_f32_16x16x32_bf16(azih, bwrh, pim[mt], 0, 0, 0);
      pim[mt] = __builtin_amdgcn_mfma_f32_16x16x32_bf16(azrh, bwil, pim[mt], 0, 0, 0);
      pim[mt] = __builtin_amdgcn_mfma_f32_16x16x32_bf16(azih, bwrl, pim[mt], 0, 0, 0);
      pim[mt] = __builtin_amdgcn_mfma_f32_16x16x32_bf16(azrl, bwih, pim[mt], 0, 0, 0);
      pim[mt] = __builtin_amdgcn_mfma_f32_16x16x32_bf16(azil, bwrh, pim[mt], 0, 0, 0);
    }
    __syncthreads();
  }

#pragma unroll
  for (int mt = 0; mt < 4; mt++) {
#pragma unroll
    for (int i = 0; i < 4; i++) {
      int b = mt * 16 + q * 4 + i;
      int h = H0 + wv * 16 + m;
      *(float2*)&pacc[(((size_t)kc * 64 + b) * 512 + h) * 2] =
          make_float2(pre[mt][i], pim[mt][i]);
    }
  }
}

// ---------------- head, split for parallelism (R11) ----------------

__global__ __launch_bounds__(256) void k_red(const float* __restrict__ pacc, float* __restrict__ upart) {
  int b = blockIdx.x;            // 0..63
  int c = blockIdx.y;            // 0..1
  int s = blockIdx.z;            // 0..3 (kc quarter)
  int t = threadIdx.x;
  int h = c * 256 + t;           // 0..511
  float sr = 0.f, si = 0.f;
  int kc0 = s * (NKC / 4);
#pragma unroll 4
  for (int kc = kc0; kc < kc0 + NKC / 4; kc++) {
    float2 v = *(const float2*)&pacc[(((size_t)kc * 64 + b) * 512 + h) * 2];
    sr += v.x; si += v.y;
  }
  float* up = upart + ((size_t)s * 64 + b) * 1024;
  up[h] = sr;
  up[512 + h] = si;
}

__global__ __launch_bounds__(320) void k_head2(const float* __restrict__ upart,
                                               const float* __restrict__ br, const float* __restrict__ bi,
                                               const float* __restrict__ actor_w, const float* __restrict__ actor_b,
                                               const float* __restrict__ critic_w, const float* __restrict__ critic_b,
                                               float* __restrict__ out) {
  __shared__ float cs[1024];
  int b = blockIdx.x, t = threadIdx.x;
  for (int k = t; k < 1024; k += 320) {
    float s = 0.f;
#pragma unroll
    for (int s4 = 0; s4 < 4; s4++) s += upart[((size_t)s4 * 64 + b) * 1024 + k];
    float bias = (k < 512) ? br[k] : bi[k - 512];
    cs[k] = fmaxf(s + bias, 0.f);
  }
  __syncthreads();
  if (t < 264) {                               // 33 outputs x 8 lanes
    int o = t >> 3, r = t & 7;
    const float* w = (o < 32) ? (actor_w + o * 1024) : critic_w;
    float acc = 0.f;
    const int j0 = r * 128;
#pragma unroll 8
    for (int j = 0; j < 128; j++) acc += cs[j0 + j] * w[j0 + j];
    acc += __shfl_down(acc, 4, 8);
    acc += __shfl_down(acc, 2, 8);
    acc += __shfl_down(acc, 1, 8);
    if (r == 0) {
      acc += (o < 32) ? actor_b[o] : critic_b[0];
      if (o < 32) out[b * 32 + o] = acc;
      else        out[2048 + b] = acc;
    }
  }
}

// ---------------- launch ----------------

extern "C" void kernel_launch(void* const* d_in, const int* in_sizes, int n_in,
                              void* d_out, int out_size, void* d_ws, size_t ws_size,
                              hipStream_t stream) {
  const float* xr   = (const float*)d_in[0];
  const float* xi   = (const float*)d_in[1];
  const float* ew   = (const float*)d_in[2];
  const float* c1wr = (const float*)d_in[3];
  const float* c1wi = (const float*)d_in[4];
  const float* c1br = (const float*)d_in[5];
  const float* c1bi = (const float*)d_in[6];
  const float* chw  = (const float*)d_in[7];
  const float* chb  = (const float*)d_in[8];
  const float* f1wr = (const float*)d_in[9];
  const float* f1wi = (const float*)d_in[10];
  const float* f1br = (const float*)d_in[11];
  const float* f1bi = (const float*)d_in[12];
  const float* cw   = (const float*)d_in[13];
  const float* cb   = (const float*)d_in[14];
  const float* aw   = (const float*)d_in[15];
  const float* ab   = (const float*)d_in[16];
  const int*   ei   = (const int*)d_in[17];
  float* out = (float*)d_out;

  char* ws = (char*)d_ws;
  size_t off = 0;
  auto alloc = [&](size_t bytes) { char* p = ws + off; off += (bytes + 255) & ~(size_t)255; return p; };
  int*   cnt      = (int*)  alloc((size_t)NN_ * 4);
  int*   rowstart = (int*)  alloc((size_t)NN_ * 4);
  float* dinv     = (float*)alloc((size_t)NN_ * 4);
  int*   btot     = (int*)  alloc((size_t)NB * 4);
  int*   bstart   = (int*)  alloc((size_t)(NB + 1) * 4);
  float* zr       = (float*)alloc((size_t)NN_ * 10 * 4);
  float* zi       = (float*)alloc((size_t)NN_ * 10 * 4);
  int2*  ecsr     = (int2*) alloc((size_t)E_ * 8);    // born at k_p2; dead after lap2cheb
  float* Y        = (float*)alloc((size_t)NN_ * 20 * 4);   // born at conv1
  float* T1       = (float*)alloc((size_t)NN_ * 20 * 4);   // born at lap1 (contiguous after Y)
  unsigned* T1h   = (unsigned*)alloc((size_t)NN_ * 10 * 4); // fp16 shadow of T1 (5.25 MB)
  // blockhist (2 MB, dead after p1scat) aliases ecsr head (ecsr born at k_p2)
  int* blockhist = (int*)ecsr;
  // recA (16 MB), dead after k_p2, aliases Y+T1 (contiguous 21 MB)
  int2* recA = (int2*)Y;
  // Yh fp16 shadow (5.25 MB, live conv1..lap1) aliases zr (born at lap2cheb)
  unsigned* Yh = (unsigned*)zr;
  // pacc (33.5 MB, born at fc1) aliases ecsr+Y+T1 (37.8 MB, all dead by then)
  float* pacc = (float*)ecsr;
  // upart (1 MB, born at k_red) aliases T1h (dead after lap2cheb)
  float* upart = (float*)T1h;

  k_p1hist<<<P1B, 256, 0, stream>>>(ei, blockhist);
  k_p1scanA<<<NB, 256, 0, stream>>>(blockhist, btot);
  k_p1scanB<<<1, 256, 0, stream>>>(btot, bstart);
  k_p1scat<<<P1B, 256, 0, stream>>>(ei, ew, blockhist, bstart, recA);
  k_p2<<<NB, 256, 0, stream>>>(recA, bstart, cnt, rowstart, dinv, ecsr);
  k_wfix<<<E_ / 256, 256, 0, stream>>>(ecsr, dinv);
  k_conv1<<<NN_ / 256, 256, 0, stream>>>(xr, xi, c1wr, c1wi, c1br, c1bi, Y, Yh);
  k_lap1<<<NN_ * 2 / 512, 512, 0, stream>>>(Y, Yh, ecsr, rowstart, cnt, T1, T1h);
  k_lap2cheb<<<NN_ * 2 / 512, 512, 0, stream>>>(Y, T1, T1h, ecsr, rowstart, cnt, chw, chb, zr, zi);
  k_fc1<<<dim3(8, NKC), 256, 0, stream>>>(zr, zi, f1wr, f1wi, pacc);
  k_red<<<dim3(64, 2, 4), 256, 0, stream>>>(pacc, upart);
  k_head2<<<B_, 320, 0, stream>>>(upart, f1br, f1bi, aw, ab, cw, cb, out);
}

// Round 13
// 338.927 us; speedup vs baseline: 1.2796x; 1.0009x over previous
//
#include <hip/hip_runtime.h>

#define NN_ 131072
#define E_  2097152
#define B_  64
#define K_  20480
#define H_  512
#define EPS_ 1e-6f
#define DEGSCALE 4194304.0f      // 2^22
#define DEGINV   (1.0f / 4194304.0f)
#define NKC 128                  // fc1 K-split chunks
#define CHUNK 160                // K_ / NKC
#define KSTEPS 5                 // CHUNK / 32 (MFMA k=32 per step)
#define LSTR 40                  // fc1 LDS row stride in fp16 elems
#define NB 1024                  // CSR buckets
#define RPB 128                  // rows per bucket (NN/NB)
#define EB 4096                  // edges per p1 block (R15: 4096 for LDS-staged writeout)
#define P1B (E_ / EB)            // 512 p1 blocks
#define EPT (EB / 256)           // 16 edges per thread

typedef __attribute__((ext_vector_type(8))) short short8;     // 8x16b (4 VGPRs)
typedef __attribute__((ext_vector_type(8))) _Float16 half8;   // 8 fp16 (4 VGPRs)
typedef __attribute__((ext_vector_type(4))) float f32x4;      // MFMA accumulator
typedef __attribute__((ext_vector_type(2))) _Float16 half2v;  // 2 fp16 in 4B

// ---------------- graph preprocessing: bucket-sort CSR, ZERO global atomics ----
// R10: global atomics write through to HBM. 2-level bucket sort.
// R13: per-row edges sorted by column CHUNK (col>>14, 8 chunks) -> lap gathers
// sweep the column space roughly in lockstep, active band mostly L2-resident.
// R15: p1scat LDS-staged bucket-ordered writeout + packed recA.
// R19/R20 falsified lap latency theory: BW pinned ~3.3 TB/s at occ 19/35/76%
// -> random-64B-line ceiling. R21: fp16 gather shadows halve gathered bytes
// (absmax 1.2e-4, passes).
// R22 neutral: AGPR folding didn't move occupancy (still ~20%).
// R23: fc1 switches to SINGLE fp16 fragments (no hi/lo split): 4 MFMAs/mt
// (vs 12), LDS 20KB (vs 40KB), half convert VALU. fp16's 11-bit mantissa
// keeps output err ~1e-4, same order as the lap fp16 error already in play.
// Fallback if absmax fails: revert fc1 to R22 split-bf16.

__global__ __launch_bounds__(256) void k_p1hist(const int* __restrict__ ei, int* __restrict__ blockhist) {
  __shared__ int h[NB];
  int t = threadIdx.x, blk = blockIdx.x;
  for (int i = t; i < NB; i += 256) h[i] = 0;
  __syncthreads();
  int e0 = blk * EB;
#pragma unroll
  for (int i = 0; i < EPT; i++) {
    int r = ei[e0 + i * 256 + t];
    atomicAdd(&h[r >> 7], 1);
  }
  __syncthreads();
  for (int i = t; i < NB; i += 256) blockhist[blk * NB + i] = h[i];
}

// per-bucket exclusive scan over the P1B block counts (in place) + bucket totals
__global__ __launch_bounds__(256) void k_p1scanA(int* __restrict__ blockhist, int* __restrict__ btot) {
  __shared__ int s[256];
  int t = threadIdx.x, b = blockIdx.x;
  int v[P1B / 256], sum = 0;
#pragma unroll
  for (int j = 0; j < P1B / 256; j++) { v[j] = blockhist[((P1B / 256) * t + j) * NB + b]; sum += v[j]; }
  s[t] = sum;
  __syncthreads();
  for (int off = 1; off < 256; off <<= 1) {
    int x = (t >= off) ? s[t - off] : 0;
    __syncthreads();
    s[t] += x;
    __syncthreads();
  }
  int o = s[t] - sum;
#pragma unroll
  for (int j = 0; j < P1B / 256; j++) { blockhist[((P1B / 256) * t + j) * NB + b] = o; o += v[j]; }
  if (t == 0) btot[b] = s[255];
}

// exclusive scan of 1024 bucket totals -> bstart[0..NB], bstart[NB]=E
__global__ __launch_bounds__(256) void k_p1scanB(const int* __restrict__ btot, int* __restrict__ bstart) {
  __shared__ int s[256];
  int t = threadIdx.x;
  int v[4], sum = 0;
#pragma unroll
  for (int j = 0; j < 4; j++) { v[j] = btot[4 * t + j]; sum += v[j]; }
  s[t] = sum;
  __syncthreads();
  for (int off = 1; off < 256; off <<= 1) {
    int x = (t >= off) ? s[t - off] : 0;
    __syncthreads();
    s[t] += x;
    __syncthreads();
  }
  int o = s[t] - sum;
#pragma unroll
  for (int j = 0; j < 4; j++) { bstart[4 * t + j] = o; o += v[j]; }
  if (t == 0) bstart[NB] = s[255];
}

// R15: LDS-staged bucket-ordered scatter. Records packed (col | lr<<17, w).
__global__ __launch_bounds__(256) void k_p1scat(const int* __restrict__ ei, const float* __restrict__ ew,
                                                const int* __restrict__ blockhist, const int* __restrict__ bstart,
                                                int2* __restrict__ recA) {
  __shared__ int loff[NB], run[NB], base2[NB], sc[256];
  __shared__ int2 Ast[EB];                 // 32 KB bucket-sorted staging
  __shared__ unsigned short bst[EB];       // bucket id of staged record
  int t = threadIdx.x, blk = blockIdx.x;
  for (int i = t; i < NB; i += 256) {
    run[i] = 0;
    base2[i] = bstart[i] + blockhist[blk * NB + i];
  }
  __syncthreads();
  int e0 = blk * EB;
  int rv[EPT], cv[EPT];
  float wv[EPT];
#pragma unroll
  for (int i = 0; i < EPT; i++) {
    int e = e0 + i * 256 + t;
    rv[i] = ei[e];
    cv[i] = ei[E_ + e];
    wv[i] = ew[e];
    atomicAdd(&run[rv[i] >> 7], 1);        // local histogram
  }
  __syncthreads();
  // exclusive scan of the 1024-entry local histogram
  int v[4], sum = 0;
#pragma unroll
  for (int j = 0; j < 4; j++) { v[j] = run[4 * t + j]; sum += v[j]; }
  sc[t] = sum;
  __syncthreads();
  for (int off = 1; off < 256; off <<= 1) {
    int x = (t >= off) ? sc[t - off] : 0;
    __syncthreads();
    sc[t] += x;
    __syncthreads();
  }
  int o = sc[t] - sum;
#pragma unroll
  for (int j = 0; j < 4; j++) { loff[4 * t + j] = o; o += v[j]; }
  __syncthreads();
  for (int i = t; i < NB; i += 256) run[i] = 0;
  __syncthreads();
  // scatter into LDS in bucket order
#pragma unroll
  for (int i = 0; i < EPT; i++) {
    int bkt = rv[i] >> 7;
    int lpos = loff[bkt] + atomicAdd(&run[bkt], 1);
    Ast[lpos] = make_int2(cv[i] | ((rv[i] & 127) << 17), __float_as_int(wv[i]));
    bst[lpos] = (unsigned short)bkt;
  }
  __syncthreads();
  // linear writeout: consecutive i within a bucket -> consecutive global pos
  for (int i = t; i < EB; i += 256) {
    int bkt = bst[i];
    recA[base2[bkt] + (i - loff[bkt])] = Ast[i];
  }
}

// per-bucket: cell = localrow*8 + colchunk. Count cells + Q22 deg -> dinv /
// cnt / rowstart; scatter chunk-sorted ecsr (w = ew*dinv[r]).
__global__ __launch_bounds__(256) void k_p2(const int2* __restrict__ recA,
                                            const int* __restrict__ bstart,
                                            int* __restrict__ cnt_g, int* __restrict__ rowstart,
                                            float* __restrict__ dinv, int2* __restrict__ ecsr) {
  __shared__ int cnt_s[1024], excl_s[1024], run_s[1024], sc[256];
  __shared__ unsigned deg_s[RPB];
  __shared__ float dl[RPB];
  int t = threadIdx.x, b = blockIdx.x;
  int b0 = bstart[b], nE = bstart[b + 1] - b0;
  for (int j = t; j < 1024; j += 256) { cnt_s[j] = 0; run_s[j] = 0; }
  if (t < RPB) deg_s[t] = 0;
  __syncthreads();
  for (int i = t; i < nE; i += 256) {
    int2 ra = recA[b0 + i];
    int lr = ((unsigned)ra.x >> 17) & 127;
    int col = ra.x & 131071;
    float w = __int_as_float(ra.y);
    atomicAdd(&cnt_s[lr * 8 + ((unsigned)col >> 14)], 1);
    atomicAdd(&deg_s[lr], (unsigned)(w * DEGSCALE + 0.5f));
  }
  __syncthreads();
  int v[4], sum = 0;
#pragma unroll
  for (int j = 0; j < 4; j++) { v[j] = cnt_s[4 * t + j]; sum += v[j]; }
  sc[t] = sum;
  __syncthreads();
  for (int off = 1; off < 256; off <<= 1) {
    int x = (t >= off) ? sc[t - off] : 0;
    __syncthreads();
    sc[t] += x;
    __syncthreads();
  }
  int o = sc[t] - sum;
#pragma unroll
  for (int j = 0; j < 4; j++) { excl_s[4 * t + j] = o; o += v[j]; }
  __syncthreads();
  if (t < RPB) {
    int row = b * RPB + t;
    int e0r = excl_s[t * 8];
    int e1r = (t < RPB - 1) ? excl_s[t * 8 + 8] : nE;
    rowstart[row] = b0 + e0r;
    cnt_g[row] = e1r - e0r;
    float d = (float)deg_s[t] * DEGINV;
    float dv = (d > 0.f) ? rsqrtf(d + EPS_) : 0.f;
    dl[t] = dv;
    dinv[row] = dv;
  }
  __syncthreads();
  for (int i = t; i < nE; i += 256) {
    int2 ra = recA[b0 + i];
    int lr = ((unsigned)ra.x >> 17) & 127;
    int col = ra.x & 131071;
    int cell = lr * 8 + ((unsigned)col >> 14);
    int pos = excl_s[cell] + atomicAdd(&run_s[cell], 1);
    float wp = __int_as_float(ra.y) * dl[lr];
    ecsr[b0 + pos] = make_int2(col, __float_as_int(wp));
  }
}

// finalize w *= dinv[col]  (keeps lap kernels unchanged)
__global__ __launch_bounds__(256) void k_wfix(int2* __restrict__ ecsr, const float* __restrict__ dinv) {
  int e = blockIdx.x * 256 + threadIdx.x;
  if (e >= E_) return;
  int2 r = ecsr[e];
  r.y = __float_as_int(__int_as_float(r.y) * dinv[r.x]);
  ecsr[e] = r;
}

// ---------------- conv1 (complex 1x1 conv + ReLU) ----------------
// Y layout: [NN][20] fp32 (0..9 real, 10..19 imag) + Yh fp16 shadow [NN][20]h.

__global__ __launch_bounds__(256) void k_conv1(const float* __restrict__ xr, const float* __restrict__ xi,
                                               const float* __restrict__ wr_g, const float* __restrict__ wi_g,
                                               const float* __restrict__ br_g, const float* __restrict__ bi_g,
                                               float* __restrict__ Y, unsigned* __restrict__ Yh) {
  __shared__ float wr[100], wi[100], br[10], bi[10];
  int t = threadIdx.x;
  if (t < 100) { wr[t] = wr_g[t]; wi[t] = wi_g[t]; }
  if (t < 10)  { br[t] = br_g[t]; bi[t] = bi_g[t]; }
  __syncthreads();
  int n = blockIdx.x * 256 + t;
  float xrv[10], xiv[10];
  const float2* a = (const float2*)(xr + (size_t)n * 10);
  const float2* b2 = (const float2*)(xi + (size_t)n * 10);
#pragma unroll
  for (int i = 0; i < 5; i++) {
    float2 v = a[i];  xrv[2 * i] = v.x; xrv[2 * i + 1] = v.y;
    float2 u = b2[i]; xiv[2 * i] = u.x; xiv[2 * i + 1] = u.y;
  }
  float out[20];
#pragma unroll
  for (int c = 0; c < 10; c++) {
    float ar = br[c], ai = bi[c];
#pragma unroll
    for (int tt = 0; tt < 10; tt++) {
      float wrc = wr[c * 10 + tt], wic = wi[c * 10 + tt];
      ar += xrv[tt] * wrc - xiv[tt] * wic;
      ai += xrv[tt] * wic + xiv[tt] * wrc;
    }
    out[c] = fmaxf(ar, 0.f);
    out[10 + c] = fmaxf(ai, 0.f);
  }
  float4* yp = (float4*)(Y + (size_t)n * 20);
#pragma unroll
  for (int i = 0; i < 5; i++)
    yp[i] = make_float4(out[4 * i], out[4 * i + 1], out[4 * i + 2], out[4 * i + 3]);
  unsigned* yh = Yh + (size_t)n * 10;
#pragma unroll
  for (int i = 0; i < 10; i++) {
    half2v hv; hv.x = (_Float16)out[2 * i]; hv.y = (_Float16)out[2 * i + 1];
    yh[i] = *(unsigned*)&hv;
  }
}

// ---------------- Laplacian pass 1: T1 = Y - S(Y) ----------------
// R18 2-lane structure (h = real/imag half), 2-wide edge unroll.
// R21: gathers from fp16 Yh (20B/lane); own row + T1 output stay fp32;
// additionally writes fp16 T1h shadow for lap2cheb's gather.

__global__ __launch_bounds__(512) void k_lap1(const float* __restrict__ Y, const unsigned* __restrict__ Yh,
                                              const int2* __restrict__ ecsr,
                                              const int* __restrict__ rowstart, const int* __restrict__ cnt,
                                              float* __restrict__ T1, unsigned* __restrict__ T1h) {
  int gid = blockIdx.x * 512 + threadIdx.x;
  int n = gid >> 1, h = gid & 1;
  float acc[10];
#pragma unroll
  for (int j = 0; j < 10; j++) acc[j] = 0.f;
  int e0 = rowstart[n], ec = cnt[n];
  int i = 0;
  for (; i + 2 <= ec; i += 2) {
    int2 ra = ecsr[e0 + i];
    int2 rb = ecsr[e0 + i + 1];
    float wa = __int_as_float(ra.y), wb = __int_as_float(rb.y);
    const unsigned* pa = Yh + (size_t)ra.x * 10 + h * 5;
    const unsigned* pb = Yh + (size_t)rb.x * 10 + h * 5;
    unsigned ua0 = pa[0], ua1 = pa[1], ua2 = pa[2], ua3 = pa[3], ua4 = pa[4];
    unsigned ub0 = pb[0], ub1 = pb[1], ub2 = pb[2], ub3 = pb[3], ub4 = pb[4];
#pragma unroll
    for (int q = 0; q < 5; q++) {
      unsigned ua = (q == 0) ? ua0 : (q == 1) ? ua1 : (q == 2) ? ua2 : (q == 3) ? ua3 : ua4;
      half2v ha = *(half2v*)&ua;
      acc[2 * q]     += wa * (float)ha.x;
      acc[2 * q + 1] += wa * (float)ha.y;
    }
#pragma unroll
    for (int q = 0; q < 5; q++) {
      unsigned ub = (q == 0) ? ub0 : (q == 1) ? ub1 : (q == 2) ? ub2 : (q == 3) ? ub3 : ub4;
      half2v hb = *(half2v*)&ub;
      acc[2 * q]     += wb * (float)hb.x;
      acc[2 * q + 1] += wb * (float)hb.y;
    }
  }
  if (i < ec) {
    int2 rec = ecsr[e0 + i];
    float w = __int_as_float(rec.y);
    const unsigned* yp = Yh + (size_t)rec.x * 10 + h * 5;
#pragma unroll
    for (int q = 0; q < 5; q++) {
      unsigned u = yp[q];
      half2v hv = *(half2v*)&u;
      acc[2 * q]     += w * (float)hv.x;
      acc[2 * q + 1] += w * (float)hv.y;
    }
  }
  const float2* yn = (const float2*)(Y + (size_t)n * 20 + h * 10);
  float2* tp = (float2*)(T1 + (size_t)n * 20 + h * 10);
  unsigned* th = T1h + (size_t)n * 10 + h * 5;
#pragma unroll
  for (int q = 0; q < 5; q++) {
    float2 v = yn[q];
    float r0 = v.x - acc[2 * q], r1 = v.y - acc[2 * q + 1];
    tp[q] = make_float2(r0, r1);
    half2v hv; hv.x = (_Float16)r0; hv.y = (_Float16)r1;
    th[q] = *(unsigned*)&hv;
  }
}

// ---------------- Laplacian pass 2 + Chebyshev combine + ReLU ----------------
// Gathers from fp16 T1h; own rows (t0, t1) and combine stay fp32.

__global__ __launch_bounds__(512) void k_lap2cheb(const float* __restrict__ Y, const float* __restrict__ T1,
                                                  const unsigned* __restrict__ T1h,
                                                  const int2* __restrict__ ecsr,
                                                  const int* __restrict__ rowstart, const int* __restrict__ cnt,
                                                  const float* __restrict__ cw_g, const float* __restrict__ cb_g,
                                                  float* __restrict__ zr, float* __restrict__ zi) {
  __shared__ float cw[300], cb[10];
  int t = threadIdx.x;
  if (t < 300) cw[t] = cw_g[t];
  if (t < 10)  cb[t] = cb_g[t];
  __syncthreads();
  int gid = blockIdx.x * 512 + t;
  int n = gid >> 1, h = gid & 1;
  float acc[10];
#pragma unroll
  for (int j = 0; j < 10; j++) acc[j] = 0.f;
  int e0 = rowstart[n], ec = cnt[n];
  int i = 0;
  for (; i + 2 <= ec; i += 2) {
    int2 ra = ecsr[e0 + i];
    int2 rb = ecsr[e0 + i + 1];
    float wa = __int_as_float(ra.y), wb = __int_as_float(rb.y);
    const unsigned* pa = T1h + (size_t)ra.x * 10 + h * 5;
    const unsigned* pb = T1h + (size_t)rb.x * 10 + h * 5;
    unsigned ua0 = pa[0], ua1 = pa[1], ua2 = pa[2], ua3 = pa[3], ua4 = pa[4];
    unsigned ub0 = pb[0], ub1 = pb[1], ub2 = pb[2], ub3 = pb[3], ub4 = pb[4];
#pragma unroll
    for (int q = 0; q < 5; q++) {
      unsigned ua = (q == 0) ? ua0 : (q == 1) ? ua1 : (q == 2) ? ua2 : (q == 3) ? ua3 : ua4;
      half2v ha = *(half2v*)&ua;
      acc[2 * q]     += wa * (float)ha.x;
      acc[2 * q + 1] += wa * (float)ha.y;
    }
#pragma unroll
    for (int q = 0; q < 5; q++) {
      unsigned ub = (q == 0) ? ub0 : (q == 1) ? ub1 : (q == 2) ? ub2 : (q == 3) ? ub3 : ub4;
      half2v hb = *(half2v*)&ub;
      acc[2 * q]     += wb * (float)hb.x;
      acc[2 * q + 1] += wb * (float)hb.y;
    }
  }
  if (i < ec) {
    int2 rec = ecsr[e0 + i];
    float w = __int_as_float(rec.y);
    const unsigned* tp = T1h + (size_t)rec.x * 10 + h * 5;
#pragma unroll
    for (int q = 0; q < 5; q++) {
      unsigned u = tp[q];
      half2v hv = *(half2v*)&u;
      acc[2 * q]     += w * (float)hv.x;
      acc[2 * q + 1] += w * (float)hv.y;
    }
  }
  float t0[10], t1v[10], t2[10];
  const float2* yn = (const float2*)(Y + (size_t)n * 20 + h * 10);
  const float2* tn = (const float2*)(T1 + (size_t)n * 20 + h * 10);
#pragma unroll
  for (int q = 0; q < 5; q++) {
    float2 v = yn[q]; t0[2 * q] = v.x; t0[2 * q + 1] = v.y;
    float2 u = tn[q]; t1v[2 * q] = u.x; t1v[2 * q + 1] = u.y;
  }
#pragma unroll
  for (int j = 0; j < 10; j++) t2[j] = 2.f * (t1v[j] - acc[j]) - t0[j];

  float outv[10];
#pragma unroll
  for (int o = 0; o < 10; o++) outv[o] = h ? 0.f : cb[o];
#pragma unroll
  for (int j = 0; j < 10; j++) {
#pragma unroll
    for (int o = 0; o < 10; o++) {
      outv[o] += t0[j] * cw[j * 10 + o] + t1v[j] * cw[100 + j * 10 + o] + t2[j] * cw[200 + j * 10 + o];
    }
  }
  float2* zp = (float2*)((h ? zi : zr) + (size_t)n * 10);
#pragma unroll
  for (int q = 0; q < 5; q++)
    zp[q] = make_float2(fmaxf(outv[2 * q], 0.f), fmaxf(outv[2 * q + 1], 0.f));
}

// ---------------- fc1 complex GEMM: single-fp16 MFMA (R23) ----------------
// 4 arrays in LDS (zr, zi, Wr, Wi as fp16), 4 MFMAs/mt/kstep. -zi via fp16
// sign-xor (exact). Issue-early prefetch retained.

__device__ __forceinline__ half8 negf16x8(half8 a) {
  union { half8 s; unsigned u[4]; } x;
  x.s = a;
#pragma unroll
  for (int j = 0; j < 4; j++) x.u[j] ^= 0x80008000u;
  return x.s;
}

#define LIDX(a, r, c) (((a) * 64 + (r)) * LSTR + (c))

__global__ __launch_bounds__(256) void k_fc1(const float* __restrict__ zr, const float* __restrict__ zi,
                                             const float* __restrict__ Wr, const float* __restrict__ Wi,
                                             float* __restrict__ pacc) {
  __shared__ unsigned short ls[4 * 64 * LSTR];   // 0 zr, 1 zi, 2 Wr, 3 Wi (fp16)
  int t = threadIdx.x;
  int hb = blockIdx.x;          // 0..7
  int kc = blockIdx.y;          // 0..NKC-1
  int H0 = hb * 64;
  int lane = t & 63, wv = t >> 6;
  int m = lane & 15, q = lane >> 4;

  int r0 = t >> 3, grp = t & 7;
  int colbase = kc * CHUNK + grp * 4;
  const float* pz  = zr + (size_t)r0 * K_ + colbase;
  const float* pzi = zi + (size_t)r0 * K_ + colbase;
  const float* pw  = Wr + (size_t)(H0 + r0) * K_ + colbase;
  const float* pwi = Wi + (size_t)(H0 + r0) * K_ + colbase;
  const size_t ROFF = (size_t)32 * K_;     // odd-p row offset (+32 rows)

  f32x4 pre[4], pim[4];
  f32x4 zero4 = {0.f, 0.f, 0.f, 0.f};
#pragma unroll
  for (int i = 0; i < 4; i++) { pre[i] = zero4; pim[i] = zero4; }

  float4 v[8];
#pragma unroll
  for (int p = 0; p < 8; p++) {
    const float* bases[4] = {pz, pzi, pw, pwi};
    v[p] = *(const float4*)(bases[p >> 1] + (p & 1) * ROFF);
  }

#pragma unroll 1
  for (int ks = 0; ks < KSTEPS; ks++) {
    // convert to fp16 + LDS write of the chunk loaded last iteration
#pragma unroll
    for (int p = 0; p < 8; p++) {
      int arr = p >> 1;
      int row = r0 + (p & 1) * 32;
      float4 f = v[p];
      half2v h0; h0.x = (_Float16)f.x; h0.y = (_Float16)f.y;
      half2v h1; h1.x = (_Float16)f.z; h1.y = (_Float16)f.w;
      *(uint2*)&ls[LIDX(arr, row, grp * 4)] = make_uint2(*(unsigned*)&h0, *(unsigned*)&h1);
    }
    __syncthreads();
    // issue-early: next chunk's loads in flight during the MFMA section
    if (ks + 1 < KSTEPS) {
      int koff = (ks + 1) * 32;
#pragma unroll
      for (int p = 0; p < 8; p++) {
        const float* bases[4] = {pz, pzi, pw, pwi};
        v[p] = *(const float4*)(bases[p >> 1] + (p & 1) * ROFF + koff);
      }
    }

    half8 bwr = *(const half8*)&ls[LIDX(2, wv * 16 + m, q * 8)];
    half8 bwi = *(const half8*)&ls[LIDX(3, wv * 16 + m, q * 8)];
#pragma unroll
    for (int mt = 0; mt < 4; mt++) {
      half8 azr = *(const half8*)&ls[LIDX(0, mt * 16 + m, q * 8)];
      half8 azi = *(const half8*)&ls[LIDX(1, mt * 16 + m, q * 8)];
      half8 nzi = negf16x8(azi);
      // re = zr*Wr - zi*Wi ; im = zr*Wi + zi*Wr
      pre[mt] = __builtin_amdgcn_mfma_f32_16x16x32_f16(azr, bwr, pre[mt], 0, 0, 0);
      pre[mt] = __builtin_amdgcn_mfma_f32_16x16x32_f16(nzi, bwi, pre[mt], 0, 0, 0);
      pim[mt] = __builtin_amdgcn_mfma_f32_16x16x32_f16(azr, bwi, pim[mt], 0, 0, 0);
      pim[mt] = __builtin_amdgcn_mfma_f32_16x16x32_f16(azi, bwr, pim[mt], 0, 0, 0);
    }
    __syncthreads();
  }

#pragma unroll
  for (int mt = 0; mt < 4; mt++) {
#pragma unroll
    for (int i = 0; i < 4; i++) {
      int b = mt * 16 + q * 4 + i;
      int h = H0 + wv * 16 + m;
      *(float2*)&pacc[(((size_t)kc * 64 + b) * 512 + h) * 2] =
          make_float2(pre[mt][i], pim[mt][i]);
    }
  }
}

// ---------------- head, split for parallelism (R11) ----------------

__global__ __launch_bounds__(256) void k_red(const float* __restrict__ pacc, float* __restrict__ upart) {
  int b = blockIdx.x;            // 0..63
  int c = blockIdx.y;            // 0..1
  int s = blockIdx.z;            // 0..3 (kc quarter)
  int t = threadIdx.x;
  int h = c * 256 + t;           // 0..511
  float sr = 0.f, si = 0.f;
  int kc0 = s * (NKC / 4);
#pragma unroll 4
  for (int kc = kc0; kc < kc0 + NKC / 4; kc++) {
    float2 v = *(const float2*)&pacc[(((size_t)kc * 64 + b) * 512 + h) * 2];
    sr += v.x; si += v.y;
  }
  float* up = upart + ((size_t)s * 64 + b) * 1024;
  up[h] = sr;
  up[512 + h] = si;
}

__global__ __launch_bounds__(320) void k_head2(const float* __restrict__ upart,
                                               const float* __restrict__ br, const float* __restrict__ bi,
                                               const float* __restrict__ actor_w, const float* __restrict__ actor_b,
                                               const float* __restrict__ critic_w, const float* __restrict__ critic_b,
                                               float* __restrict__ out) {
  __shared__ float cs[1024];
  int b = blockIdx.x, t = threadIdx.x;
  for (int k = t; k < 1024; k += 320) {
    float s = 0.f;
#pragma unroll
    for (int s4 = 0; s4 < 4; s4++) s += upart[((size_t)s4 * 64 + b) * 1024 + k];
    float bias = (k < 512) ? br[k] : bi[k - 512];
    cs[k] = fmaxf(s + bias, 0.f);
  }
  __syncthreads();
  if (t < 264) {                               // 33 outputs x 8 lanes
    int o = t >> 3, r = t & 7;
    const float* w = (o < 32) ? (actor_w + o * 1024) : critic_w;
    float acc = 0.f;
    const int j0 = r * 128;
#pragma unroll 8
    for (int j = 0; j < 128; j++) acc += cs[j0 + j] * w[j0 + j];
    acc += __shfl_down(acc, 4, 8);
    acc += __shfl_down(acc, 2, 8);
    acc += __shfl_down(acc, 1, 8);
    if (r == 0) {
      acc += (o < 32) ? actor_b[o] : critic_b[0];
      if (o < 32) out[b * 32 + o] = acc;
      else        out[2048 + b] = acc;
    }
  }
}

// ---------------- launch ----------------

extern "C" void kernel_launch(void* const* d_in, const int* in_sizes, int n_in,
                              void* d_out, int out_size, void* d_ws, size_t ws_size,
                              hipStream_t stream) {
  const float* xr   = (const float*)d_in[0];
  const float* xi   = (const float*)d_in[1];
  const float* ew   = (const float*)d_in[2];
  const float* c1wr = (const float*)d_in[3];
  const float* c1wi = (const float*)d_in[4];
  const float* c1br = (const float*)d_in[5];
  const float* c1bi = (const float*)d_in[6];
  const float* chw  = (const float*)d_in[7];
  const float* chb  = (const float*)d_in[8];
  const float* f1wr = (const float*)d_in[9];
  const float* f1wi = (const float*)d_in[10];
  const float* f1br = (const float*)d_in[11];
  const float* f1bi = (const float*)d_in[12];
  const float* cw   = (const float*)d_in[13];
  const float* cb   = (const float*)d_in[14];
  const float* aw   = (const float*)d_in[15];
  const float* ab   = (const float*)d_in[16];
  const int*   ei   = (const int*)d_in[17];
  float* out = (float*)d_out;

  char* ws = (char*)d_ws;
  size_t off = 0;
  auto alloc = [&](size_t bytes) { char* p = ws + off; off += (bytes + 255) & ~(size_t)255; return p; };
  int*   cnt      = (int*)  alloc((size_t)NN_ * 4);
  int*   rowstart = (int*)  alloc((size_t)NN_ * 4);
  float* dinv     = (float*)alloc((size_t)NN_ * 4);
  int*   btot     = (int*)  alloc((size_t)NB * 4);
  int*   bstart   = (int*)  alloc((size_t)(NB + 1) * 4);
  float* zr       = (float*)alloc((size_t)NN_ * 10 * 4);
  float* zi       = (float*)alloc((size_t)NN_ * 10 * 4);
  int2*  ecsr     = (int2*) alloc((size_t)E_ * 8);    // born at k_p2; dead after lap2cheb
  float* Y        = (float*)alloc((size_t)NN_ * 20 * 4);   // born at conv1
  float* T1       = (float*)alloc((size_t)NN_ * 20 * 4);   // born at lap1 (contiguous after Y)
  unsigned* T1h   = (unsigned*)alloc((size_t)NN_ * 10 * 4); // fp16 shadow of T1 (5.25 MB)
  // blockhist (2 MB, dead after p1scat) aliases ecsr head (ecsr born at k_p2)
  int* blockhist = (int*)ecsr;
  // recA (16 MB), dead after k_p2, aliases Y+T1 (contiguous 21 MB)
  int2* recA = (int2*)Y;
  // Yh fp16 shadow (5.25 MB, live conv1..lap1) aliases zr (born at lap2cheb)
  unsigned* Yh = (unsigned*)zr;
  // pacc (33.5 MB, born at fc1) aliases ecsr+Y+T1 (37.8 MB, all dead by then)
  float* pacc = (float*)ecsr;
  // upart (1 MB, born at k_red) aliases T1h (dead after lap2cheb)
  float* upart = (float*)T1h;

  k_p1hist<<<P1B, 256, 0, stream>>>(ei, blockhist);
  k_p1scanA<<<NB, 256, 0, stream>>>(blockhist, btot);
  k_p1scanB<<<1, 256, 0, stream>>>(btot, bstart);
  k_p1scat<<<P1B, 256, 0, stream>>>(ei, ew, blockhist, bstart, recA);
  k_p2<<<NB, 256, 0, stream>>>(recA, bstart, cnt, rowstart, dinv, ecsr);
  k_wfix<<<E_ / 256, 256, 0, stream>>>(ecsr, dinv);
  k_conv1<<<NN_ / 256, 256, 0, stream>>>(xr, xi, c1wr, c1wi, c1br, c1bi, Y, Yh);
  k_lap1<<<NN_ * 2 / 512, 512, 0, stream>>>(Y, Yh, ecsr, rowstart, cnt, T1, T1h);
  k_lap2cheb<<<NN_ * 2 / 512, 512, 0, stream>>>(Y, T1, T1h, ecsr, rowstart, cnt, chw, chb, zr, zi);
  k_fc1<<<dim3(8, NKC), 256, 0, stream>>>(zr, zi, f1wr, f1wi, pacc);
  k_red<<<dim3(64, 2, 4), 256, 0, stream>>>(pacc, upart);
  k_head2<<<B_, 320, 0, stream>>>(upart, f1br, f1bi, aw, ab, cw, cb, out);
}

// Round 14
// 337.652 us; speedup vs baseline: 1.2844x; 1.0038x over previous
//
#include <hip/hip_runtime.h>

#define NN_ 131072
#define E_  2097152
#define B_  64
#define K_  20480
#define H_  512
#define EPS_ 1e-6f
#define DEGSCALE 4194304.0f      // 2^22
#define DEGINV   (1.0f / 4194304.0f)
#define NKC 128                  // fc1 K-split chunks
#define CHUNK 160                // K_ / NKC
#define KSTEPS 5                 // CHUNK / 32 (MFMA k=32 per step)
#define LSTR 40                  // fc1 LDS row stride in fp16 elems
#define NB 1024                  // CSR buckets
#define RPB 128                  // rows per bucket (NN/NB)
#define EB 4096                  // edges per p1 block (R15: 4096 for LDS-staged writeout)
#define P1B (E_ / EB)            // 512 p1 blocks
#define EPT (EB / 256)           // 16 edges per thread

typedef __attribute__((ext_vector_type(8))) short short8;     // 8x16b (4 VGPRs)
typedef __attribute__((ext_vector_type(8))) _Float16 half8;   // 8 fp16 (4 VGPRs)
typedef __attribute__((ext_vector_type(4))) float f32x4;      // MFMA accumulator
typedef __attribute__((ext_vector_type(2))) _Float16 half2v;  // 2 fp16 in 4B

// ---------------- graph preprocessing: bucket-sort CSR, ZERO global atomics ----
// R10: global atomics write through to HBM. 2-level bucket sort.
// R13: per-row edges sorted by column CHUNK (col>>14, 8 chunks) -> lap gathers
// sweep the column space roughly in lockstep, active band mostly L2-resident.
// R15: p1scat LDS-staged bucket-ordered writeout + packed recA.
// R19/R20 falsified lap latency theory: BW pinned ~3.3 TB/s at occ 19/35/76%
// -> random-64B-line ceiling. R21: fp16 gather shadows halve gathered bytes
// (absmax 1.2e-4). R23: fc1 single-fp16 MFMA (4/mt vs 12, LDS 20KB,
// absmax 4.9e-4, passes).
// R24: fc1 kstep critical path was convert->bar->MFMA->bar with prefetch in
// flight only during the ~300cy MFMA (< 900cy HBM latency). Double-buffer
// LDS (2x20KB): ONE barrier/kstep; loads for ks+1 fly across MFMA(ks) +
// convert into the other buffer. Barriers 10->5 per block.

__global__ __launch_bounds__(256) void k_p1hist(const int* __restrict__ ei, int* __restrict__ blockhist) {
  __shared__ int h[NB];
  int t = threadIdx.x, blk = blockIdx.x;
  for (int i = t; i < NB; i += 256) h[i] = 0;
  __syncthreads();
  int e0 = blk * EB;
#pragma unroll
  for (int i = 0; i < EPT; i++) {
    int r = ei[e0 + i * 256 + t];
    atomicAdd(&h[r >> 7], 1);
  }
  __syncthreads();
  for (int i = t; i < NB; i += 256) blockhist[blk * NB + i] = h[i];
}

// per-bucket exclusive scan over the P1B block counts (in place) + bucket totals
__global__ __launch_bounds__(256) void k_p1scanA(int* __restrict__ blockhist, int* __restrict__ btot) {
  __shared__ int s[256];
  int t = threadIdx.x, b = blockIdx.x;
  int v[P1B / 256], sum = 0;
#pragma unroll
  for (int j = 0; j < P1B / 256; j++) { v[j] = blockhist[((P1B / 256) * t + j) * NB + b]; sum += v[j]; }
  s[t] = sum;
  __syncthreads();
  for (int off = 1; off < 256; off <<= 1) {
    int x = (t >= off) ? s[t - off] : 0;
    __syncthreads();
    s[t] += x;
    __syncthreads();
  }
  int o = s[t] - sum;
#pragma unroll
  for (int j = 0; j < P1B / 256; j++) { blockhist[((P1B / 256) * t + j) * NB + b] = o; o += v[j]; }
  if (t == 0) btot[b] = s[255];
}

// exclusive scan of 1024 bucket totals -> bstart[0..NB], bstart[NB]=E
__global__ __launch_bounds__(256) void k_p1scanB(const int* __restrict__ btot, int* __restrict__ bstart) {
  __shared__ int s[256];
  int t = threadIdx.x;
  int v[4], sum = 0;
#pragma unroll
  for (int j = 0; j < 4; j++) { v[j] = btot[4 * t + j]; sum += v[j]; }
  s[t] = sum;
  __syncthreads();
  for (int off = 1; off < 256; off <<= 1) {
    int x = (t >= off) ? s[t - off] : 0;
    __syncthreads();
    s[t] += x;
    __syncthreads();
  }
  int o = s[t] - sum;
#pragma unroll
  for (int j = 0; j < 4; j++) { bstart[4 * t + j] = o; o += v[j]; }
  if (t == 0) bstart[NB] = s[255];
}

// R15: LDS-staged bucket-ordered scatter. Records packed (col | lr<<17, w).
__global__ __launch_bounds__(256) void k_p1scat(const int* __restrict__ ei, const float* __restrict__ ew,
                                                const int* __restrict__ blockhist, const int* __restrict__ bstart,
                                                int2* __restrict__ recA) {
  __shared__ int loff[NB], run[NB], base2[NB], sc[256];
  __shared__ int2 Ast[EB];                 // 32 KB bucket-sorted staging
  __shared__ unsigned short bst[EB];       // bucket id of staged record
  int t = threadIdx.x, blk = blockIdx.x;
  for (int i = t; i < NB; i += 256) {
    run[i] = 0;
    base2[i] = bstart[i] + blockhist[blk * NB + i];
  }
  __syncthreads();
  int e0 = blk * EB;
  int rv[EPT], cv[EPT];
  float wv[EPT];
#pragma unroll
  for (int i = 0; i < EPT; i++) {
    int e = e0 + i * 256 + t;
    rv[i] = ei[e];
    cv[i] = ei[E_ + e];
    wv[i] = ew[e];
    atomicAdd(&run[rv[i] >> 7], 1);        // local histogram
  }
  __syncthreads();
  // exclusive scan of the 1024-entry local histogram
  int v[4], sum = 0;
#pragma unroll
  for (int j = 0; j < 4; j++) { v[j] = run[4 * t + j]; sum += v[j]; }
  sc[t] = sum;
  __syncthreads();
  for (int off = 1; off < 256; off <<= 1) {
    int x = (t >= off) ? sc[t - off] : 0;
    __syncthreads();
    sc[t] += x;
    __syncthreads();
  }
  int o = sc[t] - sum;
#pragma unroll
  for (int j = 0; j < 4; j++) { loff[4 * t + j] = o; o += v[j]; }
  __syncthreads();
  for (int i = t; i < NB; i += 256) run[i] = 0;
  __syncthreads();
  // scatter into LDS in bucket order
#pragma unroll
  for (int i = 0; i < EPT; i++) {
    int bkt = rv[i] >> 7;
    int lpos = loff[bkt] + atomicAdd(&run[bkt], 1);
    Ast[lpos] = make_int2(cv[i] | ((rv[i] & 127) << 17), __float_as_int(wv[i]));
    bst[lpos] = (unsigned short)bkt;
  }
  __syncthreads();
  // linear writeout: consecutive i within a bucket -> consecutive global pos
  for (int i = t; i < EB; i += 256) {
    int bkt = bst[i];
    recA[base2[bkt] + (i - loff[bkt])] = Ast[i];
  }
}

// per-bucket: cell = localrow*8 + colchunk. Count cells + Q22 deg -> dinv /
// cnt / rowstart; scatter chunk-sorted ecsr (w = ew*dinv[r]).
__global__ __launch_bounds__(256) void k_p2(const int2* __restrict__ recA,
                                            const int* __restrict__ bstart,
                                            int* __restrict__ cnt_g, int* __restrict__ rowstart,
                                            float* __restrict__ dinv, int2* __restrict__ ecsr) {
  __shared__ int cnt_s[1024], excl_s[1024], run_s[1024], sc[256];
  __shared__ unsigned deg_s[RPB];
  __shared__ float dl[RPB];
  int t = threadIdx.x, b = blockIdx.x;
  int b0 = bstart[b], nE = bstart[b + 1] - b0;
  for (int j = t; j < 1024; j += 256) { cnt_s[j] = 0; run_s[j] = 0; }
  if (t < RPB) deg_s[t] = 0;
  __syncthreads();
  for (int i = t; i < nE; i += 256) {
    int2 ra = recA[b0 + i];
    int lr = ((unsigned)ra.x >> 17) & 127;
    int col = ra.x & 131071;
    float w = __int_as_float(ra.y);
    atomicAdd(&cnt_s[lr * 8 + ((unsigned)col >> 14)], 1);
    atomicAdd(&deg_s[lr], (unsigned)(w * DEGSCALE + 0.5f));
  }
  __syncthreads();
  int v[4], sum = 0;
#pragma unroll
  for (int j = 0; j < 4; j++) { v[j] = cnt_s[4 * t + j]; sum += v[j]; }
  sc[t] = sum;
  __syncthreads();
  for (int off = 1; off < 256; off <<= 1) {
    int x = (t >= off) ? sc[t - off] : 0;
    __syncthreads();
    sc[t] += x;
    __syncthreads();
  }
  int o = sc[t] - sum;
#pragma unroll
  for (int j = 0; j < 4; j++) { excl_s[4 * t + j] = o; o += v[j]; }
  __syncthreads();
  if (t < RPB) {
    int row = b * RPB + t;
    int e0r = excl_s[t * 8];
    int e1r = (t < RPB - 1) ? excl_s[t * 8 + 8] : nE;
    rowstart[row] = b0 + e0r;
    cnt_g[row] = e1r - e0r;
    float d = (float)deg_s[t] * DEGINV;
    float dv = (d > 0.f) ? rsqrtf(d + EPS_) : 0.f;
    dl[t] = dv;
    dinv[row] = dv;
  }
  __syncthreads();
  for (int i = t; i < nE; i += 256) {
    int2 ra = recA[b0 + i];
    int lr = ((unsigned)ra.x >> 17) & 127;
    int col = ra.x & 131071;
    int cell = lr * 8 + ((unsigned)col >> 14);
    int pos = excl_s[cell] + atomicAdd(&run_s[cell], 1);
    float wp = __int_as_float(ra.y) * dl[lr];
    ecsr[b0 + pos] = make_int2(col, __float_as_int(wp));
  }
}

// finalize w *= dinv[col]  (keeps lap kernels unchanged)
__global__ __launch_bounds__(256) void k_wfix(int2* __restrict__ ecsr, const float* __restrict__ dinv) {
  int e = blockIdx.x * 256 + threadIdx.x;
  if (e >= E_) return;
  int2 r = ecsr[e];
  r.y = __float_as_int(__int_as_float(r.y) * dinv[r.x]);
  ecsr[e] = r;
}

// ---------------- conv1 (complex 1x1 conv + ReLU) ----------------
// Y layout: [NN][20] fp32 (0..9 real, 10..19 imag) + Yh fp16 shadow [NN][20]h.

__global__ __launch_bounds__(256) void k_conv1(const float* __restrict__ xr, const float* __restrict__ xi,
                                               const float* __restrict__ wr_g, const float* __restrict__ wi_g,
                                               const float* __restrict__ br_g, const float* __restrict__ bi_g,
                                               float* __restrict__ Y, unsigned* __restrict__ Yh) {
  __shared__ float wr[100], wi[100], br[10], bi[10];
  int t = threadIdx.x;
  if (t < 100) { wr[t] = wr_g[t]; wi[t] = wi_g[t]; }
  if (t < 10)  { br[t] = br_g[t]; bi[t] = bi_g[t]; }
  __syncthreads();
  int n = blockIdx.x * 256 + t;
  float xrv[10], xiv[10];
  const float2* a = (const float2*)(xr + (size_t)n * 10);
  const float2* b2 = (const float2*)(xi + (size_t)n * 10);
#pragma unroll
  for (int i = 0; i < 5; i++) {
    float2 v = a[i];  xrv[2 * i] = v.x; xrv[2 * i + 1] = v.y;
    float2 u = b2[i]; xiv[2 * i] = u.x; xiv[2 * i + 1] = u.y;
  }
  float out[20];
#pragma unroll
  for (int c = 0; c < 10; c++) {
    float ar = br[c], ai = bi[c];
#pragma unroll
    for (int tt = 0; tt < 10; tt++) {
      float wrc = wr[c * 10 + tt], wic = wi[c * 10 + tt];
      ar += xrv[tt] * wrc - xiv[tt] * wic;
      ai += xrv[tt] * wic + xiv[tt] * wrc;
    }
    out[c] = fmaxf(ar, 0.f);
    out[10 + c] = fmaxf(ai, 0.f);
  }
  float4* yp = (float4*)(Y + (size_t)n * 20);
#pragma unroll
  for (int i = 0; i < 5; i++)
    yp[i] = make_float4(out[4 * i], out[4 * i + 1], out[4 * i + 2], out[4 * i + 3]);
  unsigned* yh = Yh + (size_t)n * 10;
#pragma unroll
  for (int i = 0; i < 10; i++) {
    half2v hv; hv.x = (_Float16)out[2 * i]; hv.y = (_Float16)out[2 * i + 1];
    yh[i] = *(unsigned*)&hv;
  }
}

// ---------------- Laplacian pass 1: T1 = Y - S(Y) ----------------
// R18 2-lane structure (h = real/imag half), 2-wide edge unroll.
// R21: gathers from fp16 Yh (20B/lane); own row + T1 output stay fp32;
// additionally writes fp16 T1h shadow for lap2cheb's gather.

__global__ __launch_bounds__(512) void k_lap1(const float* __restrict__ Y, const unsigned* __restrict__ Yh,
                                              const int2* __restrict__ ecsr,
                                              const int* __restrict__ rowstart, const int* __restrict__ cnt,
                                              float* __restrict__ T1, unsigned* __restrict__ T1h) {
  int gid = blockIdx.x * 512 + threadIdx.x;
  int n = gid >> 1, h = gid & 1;
  float acc[10];
#pragma unroll
  for (int j = 0; j < 10; j++) acc[j] = 0.f;
  int e0 = rowstart[n], ec = cnt[n];
  int i = 0;
  for (; i + 2 <= ec; i += 2) {
    int2 ra = ecsr[e0 + i];
    int2 rb = ecsr[e0 + i + 1];
    float wa = __int_as_float(ra.y), wb = __int_as_float(rb.y);
    const unsigned* pa = Yh + (size_t)ra.x * 10 + h * 5;
    const unsigned* pb = Yh + (size_t)rb.x * 10 + h * 5;
    unsigned ua0 = pa[0], ua1 = pa[1], ua2 = pa[2], ua3 = pa[3], ua4 = pa[4];
    unsigned ub0 = pb[0], ub1 = pb[1], ub2 = pb[2], ub3 = pb[3], ub4 = pb[4];
#pragma unroll
    for (int q = 0; q < 5; q++) {
      unsigned ua = (q == 0) ? ua0 : (q == 1) ? ua1 : (q == 2) ? ua2 : (q == 3) ? ua3 : ua4;
      half2v ha = *(half2v*)&ua;
      acc[2 * q]     += wa * (float)ha.x;
      acc[2 * q + 1] += wa * (float)ha.y;
    }
#pragma unroll
    for (int q = 0; q < 5; q++) {
      unsigned ub = (q == 0) ? ub0 : (q == 1) ? ub1 : (q == 2) ? ub2 : (q == 3) ? ub3 : ub4;
      half2v hb = *(half2v*)&ub;
      acc[2 * q]     += wb * (float)hb.x;
      acc[2 * q + 1] += wb * (float)hb.y;
    }
  }
  if (i < ec) {
    int2 rec = ecsr[e0 + i];
    float w = __int_as_float(rec.y);
    const unsigned* yp = Yh + (size_t)rec.x * 10 + h * 5;
#pragma unroll
    for (int q = 0; q < 5; q++) {
      unsigned u = yp[q];
      half2v hv = *(half2v*)&u;
      acc[2 * q]     += w * (float)hv.x;
      acc[2 * q + 1] += w * (float)hv.y;
    }
  }
  const float2* yn = (const float2*)(Y + (size_t)n * 20 + h * 10);
  float2* tp = (float2*)(T1 + (size_t)n * 20 + h * 10);
  unsigned* th = T1h + (size_t)n * 10 + h * 5;
#pragma unroll
  for (int q = 0; q < 5; q++) {
    float2 v = yn[q];
    float r0 = v.x - acc[2 * q], r1 = v.y - acc[2 * q + 1];
    tp[q] = make_float2(r0, r1);
    half2v hv; hv.x = (_Float16)r0; hv.y = (_Float16)r1;
    th[q] = *(unsigned*)&hv;
  }
}

// ---------------- Laplacian pass 2 + Chebyshev combine + ReLU ----------------
// Gathers from fp16 T1h; own rows (t0, t1) and combine stay fp32.

__global__ __launch_bounds__(512) void k_lap2cheb(const float* __restrict__ Y, const float* __restrict__ T1,
                                                  const unsigned* __restrict__ T1h,
                                                  const int2* __restrict__ ecsr,
                                                  const int* __restrict__ rowstart, const int* __restrict__ cnt,
                                                  const float* __restrict__ cw_g, const float* __restrict__ cb_g,
                                                  float* __restrict__ zr, float* __restrict__ zi) {
  __shared__ float cw[300], cb[10];
  int t = threadIdx.x;
  if (t < 300) cw[t] = cw_g[t];
  if (t < 10)  cb[t] = cb_g[t];
  __syncthreads();
  int gid = blockIdx.x * 512 + t;
  int n = gid >> 1, h = gid & 1;
  float acc[10];
#pragma unroll
  for (int j = 0; j < 10; j++) acc[j] = 0.f;
  int e0 = rowstart[n], ec = cnt[n];
  int i = 0;
  for (; i + 2 <= ec; i += 2) {
    int2 ra = ecsr[e0 + i];
    int2 rb = ecsr[e0 + i + 1];
    float wa = __int_as_float(ra.y), wb = __int_as_float(rb.y);
    const unsigned* pa = T1h + (size_t)ra.x * 10 + h * 5;
    const unsigned* pb = T1h + (size_t)rb.x * 10 + h * 5;
    unsigned ua0 = pa[0], ua1 = pa[1], ua2 = pa[2], ua3 = pa[3], ua4 = pa[4];
    unsigned ub0 = pb[0], ub1 = pb[1], ub2 = pb[2], ub3 = pb[3], ub4 = pb[4];
#pragma unroll
    for (int q = 0; q < 5; q++) {
      unsigned ua = (q == 0) ? ua0 : (q == 1) ? ua1 : (q == 2) ? ua2 : (q == 3) ? ua3 : ua4;
      half2v ha = *(half2v*)&ua;
      acc[2 * q]     += wa * (float)ha.x;
      acc[2 * q + 1] += wa * (float)ha.y;
    }
#pragma unroll
    for (int q = 0; q < 5; q++) {
      unsigned ub = (q == 0) ? ub0 : (q == 1) ? ub1 : (q == 2) ? ub2 : (q == 3) ? ub3 : ub4;
      half2v hb = *(half2v*)&ub;
      acc[2 * q]     += wb * (float)hb.x;
      acc[2 * q + 1] += wb * (float)hb.y;
    }
  }
  if (i < ec) {
    int2 rec = ecsr[e0 + i];
    float w = __int_as_float(rec.y);
    const unsigned* tp = T1h + (size_t)rec.x * 10 + h * 5;
#pragma unroll
    for (int q = 0; q < 5; q++) {
      unsigned u = tp[q];
      half2v hv = *(half2v*)&u;
      acc[2 * q]     += w * (float)hv.x;
      acc[2 * q + 1] += w * (float)hv.y;
    }
  }
  float t0[10], t1v[10], t2[10];
  const float2* yn = (const float2*)(Y + (size_t)n * 20 + h * 10);
  const float2* tn = (const float2*)(T1 + (size_t)n * 20 + h * 10);
#pragma unroll
  for (int q = 0; q < 5; q++) {
    float2 v = yn[q]; t0[2 * q] = v.x; t0[2 * q + 1] = v.y;
    float2 u = tn[q]; t1v[2 * q] = u.x; t1v[2 * q + 1] = u.y;
  }
#pragma unroll
  for (int j = 0; j < 10; j++) t2[j] = 2.f * (t1v[j] - acc[j]) - t0[j];

  float outv[10];
#pragma unroll
  for (int o = 0; o < 10; o++) outv[o] = h ? 0.f : cb[o];
#pragma unroll
  for (int j = 0; j < 10; j++) {
#pragma unroll
    for (int o = 0; o < 10; o++) {
      outv[o] += t0[j] * cw[j * 10 + o] + t1v[j] * cw[100 + j * 10 + o] + t2[j] * cw[200 + j * 10 + o];
    }
  }
  float2* zp = (float2*)((h ? zi : zr) + (size_t)n * 10);
#pragma unroll
  for (int q = 0; q < 5; q++)
    zp[q] = make_float2(fmaxf(outv[2 * q], 0.f), fmaxf(outv[2 * q + 1], 0.f));
}

// ---------------- fc1 complex GEMM: single-fp16 MFMA, double-buffered (R24) ----
// 2 x 20KB LDS buffers; one barrier per kstep; loads for ks+1 in flight
// across MFMA(ks) + convert. -zi via fp16 sign-xor (exact).

__device__ __forceinline__ half8 negf16x8(half8 a) {
  union { half8 s; unsigned u[4]; } x;
  x.s = a;
#pragma unroll
  for (int j = 0; j < 4; j++) x.u[j] ^= 0x80008000u;
  return x.s;
}

#define LIDX(a, r, c) (((a) * 64 + (r)) * LSTR + (c))
#define LBUF (4 * 64 * LSTR)

__global__ __launch_bounds__(256) void k_fc1(const float* __restrict__ zr, const float* __restrict__ zi,
                                             const float* __restrict__ Wr, const float* __restrict__ Wi,
                                             float* __restrict__ pacc) {
  __shared__ unsigned short ls[2 * LBUF];   // double buffer: 0 zr,1 zi,2 Wr,3 Wi (fp16) each
  int t = threadIdx.x;
  int hb = blockIdx.x;          // 0..7
  int kc = blockIdx.y;          // 0..NKC-1
  int H0 = hb * 64;
  int lane = t & 63, wv = t >> 6;
  int m = lane & 15, q = lane >> 4;

  int r0 = t >> 3, grp = t & 7;
  int colbase = kc * CHUNK + grp * 4;
  const float* pz  = zr + (size_t)r0 * K_ + colbase;
  const float* pzi = zi + (size_t)r0 * K_ + colbase;
  const float* pw  = Wr + (size_t)(H0 + r0) * K_ + colbase;
  const float* pwi = Wi + (size_t)(H0 + r0) * K_ + colbase;
  const size_t ROFF = (size_t)32 * K_;     // odd-p row offset (+32 rows)

  f32x4 pre[4], pim[4];
  f32x4 zero4 = {0.f, 0.f, 0.f, 0.f};
#pragma unroll
  for (int i = 0; i < 4; i++) { pre[i] = zero4; pim[i] = zero4; }

  float4 v[8];
#pragma unroll
  for (int p = 0; p < 8; p++) {
    const float* bases[4] = {pz, pzi, pw, pwi};
    v[p] = *(const float4*)(bases[p >> 1] + (p & 1) * ROFF);
  }
  // prologue: convert ks=0 into buf0
#pragma unroll
  for (int p = 0; p < 8; p++) {
    int arr = p >> 1;
    int row = r0 + (p & 1) * 32;
    float4 f = v[p];
    half2v h0; h0.x = (_Float16)f.x; h0.y = (_Float16)f.y;
    half2v h1; h1.x = (_Float16)f.z; h1.y = (_Float16)f.w;
    *(uint2*)&ls[LIDX(arr, row, grp * 4)] = make_uint2(*(unsigned*)&h0, *(unsigned*)&h1);
  }

  int cur = 0;
#pragma unroll 1
  for (int ks = 0; ks < KSTEPS; ks++) {
    __syncthreads();                       // buf[cur] complete for all waves
    // issue loads for ks+1 (in flight across MFMA + convert)
    if (ks + 1 < KSTEPS) {
      int koff = (ks + 1) * 32;
#pragma unroll
      for (int p = 0; p < 8; p++) {
        const float* bases[4] = {pz, pzi, pw, pwi};
        v[p] = *(const float4*)(bases[p >> 1] + (p & 1) * ROFF + koff);
      }
    }

    const unsigned short* lb = ls + cur * LBUF;
    half8 bwr = *(const half8*)&lb[LIDX(2, wv * 16 + m, q * 8)];
    half8 bwi = *(const half8*)&lb[LIDX(3, wv * 16 + m, q * 8)];
#pragma unroll
    for (int mt = 0; mt < 4; mt++) {
      half8 azr = *(const half8*)&lb[LIDX(0, mt * 16 + m, q * 8)];
      half8 azi = *(const half8*)&lb[LIDX(1, mt * 16 + m, q * 8)];
      half8 nzi = negf16x8(azi);
      // re = zr*Wr - zi*Wi ; im = zr*Wi + zi*Wr
      pre[mt] = __builtin_amdgcn_mfma_f32_16x16x32_f16(azr, bwr, pre[mt], 0, 0, 0);
      pre[mt] = __builtin_amdgcn_mfma_f32_16x16x32_f16(nzi, bwi, pre[mt], 0, 0, 0);
      pim[mt] = __builtin_amdgcn_mfma_f32_16x16x32_f16(azr, bwi, pim[mt], 0, 0, 0);
      pim[mt] = __builtin_amdgcn_mfma_f32_16x16x32_f16(azi, bwr, pim[mt], 0, 0, 0);
    }
    // convert ks+1 into the other buffer (waits on v; next barrier protects reads)
    if (ks + 1 < KSTEPS) {
      unsigned short* lo = ls + (cur ^ 1) * LBUF;
#pragma unroll
      for (int p = 0; p < 8; p++) {
        int arr = p >> 1;
        int row = r0 + (p & 1) * 32;
        float4 f = v[p];
        half2v h0; h0.x = (_Float16)f.x; h0.y = (_Float16)f.y;
        half2v h1; h1.x = (_Float16)f.z; h1.y = (_Float16)f.w;
        *(uint2*)&lo[LIDX(arr, row, grp * 4)] = make_uint2(*(unsigned*)&h0, *(unsigned*)&h1);
      }
    }
    cur ^= 1;
  }

#pragma unroll
  for (int mt = 0; mt < 4; mt++) {
#pragma unroll
    for (int i = 0; i < 4; i++) {
      int b = mt * 16 + q * 4 + i;
      int h = H0 + wv * 16 + m;
      *(float2*)&pacc[(((size_t)kc * 64 + b) * 512 + h) * 2] =
          make_float2(pre[mt][i], pim[mt][i]);
    }
  }
}

// ---------------- head, split for parallelism (R11) ----------------

__global__ __launch_bounds__(256) void k_red(const float* __restrict__ pacc, float* __restrict__ upart) {
  int b = blockIdx.x;            // 0..63
  int c = blockIdx.y;            // 0..1
  int s = blockIdx.z;            // 0..3 (kc quarter)
  int t = threadIdx.x;
  int h = c * 256 + t;           // 0..511
  float sr = 0.f, si = 0.f;
  int kc0 = s * (NKC / 4);
#pragma unroll 4
  for (int kc = kc0; kc < kc0 + NKC / 4; kc++) {
    float2 v = *(const float2*)&pacc[(((size_t)kc * 64 + b) * 512 + h) * 2];
    sr += v.x; si += v.y;
  }
  float* up = upart + ((size_t)s * 64 + b) * 1024;
  up[h] = sr;
  up[512 + h] = si;
}

__global__ __launch_bounds__(320) void k_head2(const float* __restrict__ upart,
                                               const float* __restrict__ br, const float* __restrict__ bi,
                                               const float* __restrict__ actor_w, const float* __restrict__ actor_b,
                                               const float* __restrict__ critic_w, const float* __restrict__ critic_b,
                                               float* __restrict__ out) {
  __shared__ float cs[1024];
  int b = blockIdx.x, t = threadIdx.x;
  for (int k = t; k < 1024; k += 320) {
    float s = 0.f;
#pragma unroll
    for (int s4 = 0; s4 < 4; s4++) s += upart[((size_t)s4 * 64 + b) * 1024 + k];
    float bias = (k < 512) ? br[k] : bi[k - 512];
    cs[k] = fmaxf(s + bias, 0.f);
  }
  __syncthreads();
  if (t < 264) {                               // 33 outputs x 8 lanes
    int o = t >> 3, r = t & 7;
    const float* w = (o < 32) ? (actor_w + o * 1024) : critic_w;
    float acc = 0.f;
    const int j0 = r * 128;
#pragma unroll 8
    for (int j = 0; j < 128; j++) acc += cs[j0 + j] * w[j0 + j];
    acc += __shfl_down(acc, 4, 8);
    acc += __shfl_down(acc, 2, 8);
    acc += __shfl_down(acc, 1, 8);
    if (r == 0) {
      acc += (o < 32) ? actor_b[o] : critic_b[0];
      if (o < 32) out[b * 32 + o] = acc;
      else        out[2048 + b] = acc;
    }
  }
}

// ---------------- launch ----------------

extern "C" void kernel_launch(void* const* d_in, const int* in_sizes, int n_in,
                              void* d_out, int out_size, void* d_ws, size_t ws_size,
                              hipStream_t stream) {
  const float* xr   = (const float*)d_in[0];
  const float* xi   = (const float*)d_in[1];
  const float* ew   = (const float*)d_in[2];
  const float* c1wr = (const float*)d_in[3];
  const float* c1wi = (const float*)d_in[4];
  const float* c1br = (const float*)d_in[5];
  const float* c1bi = (const float*)d_in[6];
  const float* chw  = (const float*)d_in[7];
  const float* chb  = (const float*)d_in[8];
  const float* f1wr = (const float*)d_in[9];
  const float* f1wi = (const float*)d_in[10];
  const float* f1br = (const float*)d_in[11];
  const float* f1bi = (const float*)d_in[12];
  const float* cw   = (const float*)d_in[13];
  const float* cb   = (const float*)d_in[14];
  const float* aw   = (const float*)d_in[15];
  const float* ab   = (const float*)d_in[16];
  const int*   ei   = (const int*)d_in[17];
  float* out = (float*)d_out;

  char* ws = (char*)d_ws;
  size_t off = 0;
  auto alloc = [&](size_t bytes) { char* p = ws + off; off += (bytes + 255) & ~(size_t)255; return p; };
  int*   cnt      = (int*)  alloc((size_t)NN_ * 4);
  int*   rowstart = (int*)  alloc((size_t)NN_ * 4);
  float* dinv     = (float*)alloc((size_t)NN_ * 4);
  int*   btot     = (int*)  alloc((size_t)NB * 4);
  int*   bstart   = (int*)  alloc((size_t)(NB + 1) * 4);
  float* zr       = (float*)alloc((size_t)NN_ * 10 * 4);
  float* zi       = (float*)alloc((size_t)NN_ * 10 * 4);
  int2*  ecsr     = (int2*) alloc((size_t)E_ * 8);    // born at k_p2; dead after lap2cheb
  float* Y        = (float*)alloc((size_t)NN_ * 20 * 4);   // born at conv1
  float* T1       = (float*)alloc((size_t)NN_ * 20 * 4);   // born at lap1 (contiguous after Y)
  unsigned* T1h   = (unsigned*)alloc((size_t)NN_ * 10 * 4); // fp16 shadow of T1 (5.25 MB)
  // blockhist (2 MB, dead after p1scat) aliases ecsr head (ecsr born at k_p2)
  int* blockhist = (int*)ecsr;
  // recA (16 MB), dead after k_p2, aliases Y+T1 (contiguous 21 MB)
  int2* recA = (int2*)Y;
  // Yh fp16 shadow (5.25 MB, live conv1..lap1) aliases zr (born at lap2cheb)
  unsigned* Yh = (unsigned*)zr;
  // pacc (33.5 MB, born at fc1) aliases ecsr+Y+T1 (37.8 MB, all dead by then)
  float* pacc = (float*)ecsr;
  // upart (1 MB, born at k_red) aliases T1h (dead after lap2cheb)
  float* upart = (float*)T1h;

  k_p1hist<<<P1B, 256, 0, stream>>>(ei, blockhist);
  k_p1scanA<<<NB, 256, 0, stream>>>(blockhist, btot);
  k_p1scanB<<<1, 256, 0, stream>>>(btot, bstart);
  k_p1scat<<<P1B, 256, 0, stream>>>(ei, ew, blockhist, bstart, recA);
  k_p2<<<NB, 256, 0, stream>>>(recA, bstart, cnt, rowstart, dinv, ecsr);
  k_wfix<<<E_ / 256, 256, 0, stream>>>(ecsr, dinv);
  k_conv1<<<NN_ / 256, 256, 0, stream>>>(xr, xi, c1wr, c1wi, c1br, c1bi, Y, Yh);
  k_lap1<<<NN_ * 2 / 512, 512, 0, stream>>>(Y, Yh, ecsr, rowstart, cnt, T1, T1h);
  k_lap2cheb<<<NN_ * 2 / 512, 512, 0, stream>>>(Y, T1, T1h, ecsr, rowstart, cnt, chw, chb, zr, zi);
  k_fc1<<<dim3(8, NKC), 256, 0, stream>>>(zr, zi, f1wr, f1wi, pacc);
  k_red<<<dim3(64, 2, 4), 256, 0, stream>>>(pacc, upart);
  k_head2<<<B_, 320, 0, stream>>>(upart, f1br, f1bi, aw, ab, cw, cb, out);
}